// Round 3
// baseline (703.711 us; speedup 1.0000x reference)
//
#include <hip/hip_runtime.h>
#include <math.h>

#define NN 50000
#define EE 800000
#define ET 850000    // EE + NN self loops
#define FIN 128
#define HD 64
#define NH 4
#define NGR 64
#define NCL 10
#define NEG 0.2f
#define MAXDEG 128

typedef unsigned short u16;
typedef unsigned int u32;

__device__ __forceinline__ float lrelu(float x){ return x > 0.f ? x : NEG * x; }

__device__ __forceinline__ float wsum(float v){
#pragma unroll
  for (int o = 32; o > 0; o >>= 1) v += __shfl_xor(v, o, 64);
  return v;
}
__device__ __forceinline__ float wmax(float v){
#pragma unroll
  for (int o = 32; o > 0; o >>= 1) v = fmaxf(v, __shfl_xor(v, o, 64));
  return v;
}
__device__ __forceinline__ int esrc(const int* ei, int e){ return e < EE ? ei[e] : e - EE; }
__device__ __forceinline__ int edst(const int* ei, int e){ return e < EE ? ei[EE + e] : e - EE; }

__device__ __forceinline__ unsigned f2key(float f){
  unsigned u = __float_as_uint(f);
  return (u & 0x80000000u) ? ~u : (u | 0x80000000u);
}
__device__ __forceinline__ float key2f(unsigned k){
  return (k & 0x80000000u) ? __uint_as_float(k & 0x7fffffffu) : __uint_as_float(~k);
}

// bf16 pack (RNE) / unpack
__device__ __forceinline__ u16 f2b(float f){
  u32 u = __float_as_uint(f);
  u32 r = (u + 0x7FFFu + ((u >> 16) & 1u)) >> 16;
  return (u16)r;
}
__device__ __forceinline__ float b2f(u16 b){ return __uint_as_float(((u32)b) << 16); }

// wave-uniform register broadcast
__device__ __forceinline__ float rlane(float v, int l){
  return __uint_as_float(__builtin_amdgcn_readlane(__float_as_uint(v), l));
}

// ---------- dense kernels: register-held W, readlane x-broadcast ----------

#define PQ 8
#define P_ITERS 25
#define P_NPB (PQ*P_ITERS)   // 200
// h0 = relu(x @ W_proj + b_proj)   [NN,128]@[128,64]; wave w owns k in [w*32, w*32+32)
__global__ __launch_bounds__(256) void k_proj(const float* __restrict__ x, const float* __restrict__ Wp,
                       const float* __restrict__ bp, float* __restrict__ h0){
  int t = threadIdx.x, w = t >> 6, lane = t & 63;
  int half = lane >> 5, kk32 = lane & 31;
  float Wreg[32];
#pragma unroll
  for (int kk = 0; kk < 32; ++kk) Wreg[kk] = Wp[(w*32 + kk)*HD + lane];
  float bj = bp[lane];
  __shared__ float sred[4][PQ][HD];
  int n0 = blockIdx.x * P_NPB;
  float xr[PQ/2], xn[PQ/2];
  // xr[j]: x[n0+2j+half][w*32 + kk32]
#define P_LOADX(nb, dst) { \
  _Pragma("unroll") \
  for (int j = 0; j < PQ/2; ++j){ \
    int nn = (nb) + 2*j + half; \
    dst[j] = (nn < NN) ? x[(size_t)nn*FIN + w*32 + kk32] : 0.f; \
  } }
  P_LOADX(n0, xr)
  for (int it = 0; it < P_ITERS; ++it){
    int nb = n0 + it*PQ;
    if (nb >= NN) break;
    if (it + 1 < P_ITERS) P_LOADX(nb + PQ, xn)
    float acc[PQ];
#pragma unroll
    for (int q = 0; q < PQ; ++q) acc[q] = 0.f;
#pragma unroll
    for (int kk = 0; kk < 32; ++kk){
      float wv = Wreg[kk];
#pragma unroll
      for (int j = 0; j < PQ/2; ++j){
        acc[2*j]   = fmaf(rlane(xr[j], kk),      wv, acc[2*j]);
        acc[2*j+1] = fmaf(rlane(xr[j], kk + 32), wv, acc[2*j+1]);
      }
    }
    __syncthreads();
#pragma unroll
    for (int q = 0; q < PQ; ++q) sred[w][q][lane] = acc[q];
    __syncthreads();
#pragma unroll
    for (int qq = 0; qq < 2; ++qq){
      int q = 2*w + qq, nn = nb + q;
      if (nn < NN){
        float v = sred[0][q][lane] + sred[1][q][lane] + sred[2][q][lane] + sred[3][q][lane] + bj;
        h0[(size_t)nn*HD + lane] = fmaxf(v, 0.f);
      }
    }
#pragma unroll
    for (int j = 0; j < PQ/2; ++j) xr[j] = xn[j];
  }
}

#define F1Q 8
#define F1_ITERS 25
#define F1_NPB (F1Q*F1_ITERS)   // 200
// h1b = bf16(h0 @ W1) [NN,64]@[64,256]; a_s1/a_d1 f32 dots. thread t = output col; wave = head.
__global__ __launch_bounds__(256) void k_feat1(const float* __restrict__ h0, const float* __restrict__ W1,
                        const float* __restrict__ as, const float* __restrict__ ad,
                        u16* __restrict__ h1b, float* __restrict__ a_s, float* __restrict__ a_d){
  int t = threadIdx.x, w = t >> 6, lane = t & 63;
  float Wreg[64];
#pragma unroll
  for (int kk = 0; kk < 64; ++kk) Wreg[kk] = W1[kk*256 + t];
  float asj = as[t], adj = ad[t];
  int n0 = blockIdx.x * F1_NPB;
  float xr[F1Q], xn[F1Q];
#define F1_LOADX(nb, dst) { \
  _Pragma("unroll") \
  for (int q = 0; q < F1Q; ++q){ \
    int nn = (nb) + q; \
    dst[q] = (nn < NN) ? h0[(size_t)nn*HD + lane] : 0.f; \
  } }
  F1_LOADX(n0, xr)
  for (int it = 0; it < F1_ITERS; ++it){
    int nb = n0 + it*F1Q;
    if (nb >= NN) break;
    if (it + 1 < F1_ITERS) F1_LOADX(nb + F1Q, xn)
    float acc[F1Q];
#pragma unroll
    for (int q = 0; q < F1Q; ++q) acc[q] = 0.f;
#pragma unroll
    for (int kk = 0; kk < 64; ++kk){
      float wv = Wreg[kk];
#pragma unroll
      for (int q = 0; q < F1Q; ++q) acc[q] = fmaf(rlane(xr[q], kk), wv, acc[q]);
    }
#pragma unroll
    for (int q = 0; q < F1Q; ++q){
      int nn = nb + q;
      if (nn < NN){
        h1b[(size_t)nn*256 + t] = f2b(acc[q]);
        float vs = wsum(acc[q] * asj);
        float vd = wsum(acc[q] * adj);
        if (lane == 0){ a_s[nn*NH + w] = vs; a_d[nn*NH + w] = vd; }
      }
    }
#pragma unroll
    for (int q = 0; q < F1Q; ++q) xr[q] = xn[q];
  }
}

#define F2Q 8
#define F2_ITERS 25
#define F2_NPB (F2Q*F2_ITERS)   // 200
// h2b = bf16(h1out @ W2) [NN,256]@[256,64]; a_s2/a_d2. wave w owns k in [w*64, w*64+64)
__global__ __launch_bounds__(256) void k_feat2(const float* __restrict__ h1out, const float* __restrict__ W2,
                        const float* __restrict__ as, const float* __restrict__ ad,
                        u16* __restrict__ h2b, float* __restrict__ a_s, float* __restrict__ a_d){
  int t = threadIdx.x, w = t >> 6, lane = t & 63;
  float Wreg[64];
#pragma unroll
  for (int kk = 0; kk < 64; ++kk) Wreg[kk] = W2[(w*64 + kk)*HD + lane];
  float asl = as[lane], adl = ad[lane];
  __shared__ float sred[4][F2Q][HD];
  int n0 = blockIdx.x * F2_NPB;
  float xr[F2Q], xn[F2Q];
#define F2_LOADX(nb, dst) { \
  _Pragma("unroll") \
  for (int q = 0; q < F2Q; ++q){ \
    int nn = (nb) + q; \
    dst[q] = (nn < NN) ? h1out[(size_t)nn*256 + w*64 + lane] : 0.f; \
  } }
  F2_LOADX(n0, xr)
  for (int it = 0; it < F2_ITERS; ++it){
    int nb = n0 + it*F2Q;
    if (nb >= NN) break;
    if (it + 1 < F2_ITERS) F2_LOADX(nb + F2Q, xn)
    float acc[F2Q];
#pragma unroll
    for (int q = 0; q < F2Q; ++q) acc[q] = 0.f;
#pragma unroll
    for (int kk = 0; kk < 64; ++kk){
      float wv = Wreg[kk];
#pragma unroll
      for (int q = 0; q < F2Q; ++q) acc[q] = fmaf(rlane(xr[q], kk), wv, acc[q]);
    }
    __syncthreads();
#pragma unroll
    for (int q = 0; q < F2Q; ++q) sred[w][q][lane] = acc[q];
    __syncthreads();
#pragma unroll
    for (int qq = 0; qq < 2; ++qq){
      int q = 2*w + qq, nn = nb + q;
      if (nn < NN){
        float v = sred[0][q][lane] + sred[1][q][lane] + sred[2][q][lane] + sred[3][q][lane];
        float vs = wsum(v * asl);
        float vd = wsum(v * adl);
        h2b[(size_t)nn*HD + lane] = f2b(v);
        if (lane == 0){ a_s[nn] = vs; a_d[nn] = vd; }
      }
    }
#pragma unroll
    for (int q = 0; q < F2Q; ++q) xr[q] = xn[q];
  }
}

// ---------- CSR build ----------

__global__ void k_hist(const int* __restrict__ ei, int* __restrict__ cnt){
  int e = blockIdx.x*256 + threadIdx.x;
  if (e < ET) atomicAdd(&cnt[edst(ei, e)], 1);
}

__global__ void k_bsum(const int* __restrict__ cnt, int* __restrict__ bsums){
  int b = blockIdx.x, t = threadIdx.x;
  int i = b*256 + t;
  int v = (i < NN) ? cnt[i] : 0;
  float s = wsum((float)v);
  __shared__ float ws4[4];
  if ((t & 63) == 0) ws4[t >> 6] = s;
  __syncthreads();
  if (t == 0) bsums[b] = (int)(ws4[0] + ws4[1] + ws4[2] + ws4[3] + 0.5f);
}

// parallel exclusive scan over block sums (nb <= 256)
__global__ void k_boff(const int* __restrict__ bsums, int* __restrict__ boffs, int nb){
  __shared__ int s[256];
  int t = threadIdx.x;
  int v = (t < nb) ? bsums[t] : 0;
  s[t] = v; __syncthreads();
  for (int d = 1; d < 256; d <<= 1){
    int xv = (t >= d) ? s[t-d] : 0;
    __syncthreads();
    s[t] += xv;
    __syncthreads();
  }
  if (t < nb) boffs[t] = s[t] - v;
}

__global__ void k_off(const int* __restrict__ cnt, const int* __restrict__ boffs,
                      int* __restrict__ off, int* __restrict__ pos){
  int b = blockIdx.x, t = threadIdx.x;
  int i = b*256 + t;
  __shared__ int s[256];
  int v = (i < NN) ? cnt[i] : 0;
  s[t] = v; __syncthreads();
  for (int d = 1; d < 256; d <<= 1){
    int xv = (t >= d) ? s[t-d] : 0;
    __syncthreads();
    s[t] += xv;
    __syncthreads();
  }
  int excl = s[t] - v;
  if (i < NN){ int o = boffs[b] + excl; off[i] = o; pos[i] = o; }
  if (i == NN - 1) off[NN] = boffs[b] + s[t];
}

__global__ void k_scatter(const int* __restrict__ ei, int* __restrict__ pos, int* __restrict__ csrc){
  int e = blockIdx.x*256 + threadIdx.x;
  if (e < ET){
    int d = edst(ei, e);
    int idx = atomicAdd(&pos[d], 1);
    csrc[idx] = esrc(ei, e);
  }
}

// ---------- GAT aggregation (bf16 payload gather) ----------

__global__ __launch_bounds__(256) void k_gat1(const u16* __restrict__ h1b, const float* __restrict__ a_s,
                       const float* __restrict__ a_d, const int* __restrict__ off,
                       const int* __restrict__ csrc, const float* __restrict__ b1,
                       float* __restrict__ h1out){
  int n = blockIdx.x;
  int h = threadIdx.x >> 6, lane = threadIdx.x & 63;   // wave == head
  int e0 = off[n], e1 = off[n+1], deg = e1 - e0;
  float adst = a_d[n*NH + h];
  float bv = b1[h*HD + lane];
  float acc = 0.f, inv;
  const u16* base = h1b + h*HD + lane;
  if (deg <= MAXDEG){
    int sA = 0, sB = 0;
    float alA = -3.0e38f, alB = -3.0e38f;
    if (lane < deg){
      sA = csrc[e0 + lane];
      alA = lrelu(a_s[sA*NH + h] + adst);
    }
    if (64 + lane < deg){
      sB = csrc[e0 + 64 + lane];
      alB = lrelu(a_s[sB*NH + h] + adst);
    }
    float m = wmax(fmaxf(alA, alB));
    float wA = (lane < deg)      ? __expf(alA - m) : 0.f;
    float wB = (64 + lane < deg) ? __expf(alB - m) : 0.f;
    float se = wsum(wA + wB);
    inv = 1.f / (se + 1e-16f);
    int idx = 0;
    for (; idx + 4 <= deg; idx += 4){
      int i0 = idx, i1 = idx+1, i2 = idx+2, i3 = idx+3;
      int s0 = (i0 < 64) ? __shfl(sA, i0, 64) : __shfl(sB, i0-64, 64);
      int s1 = (i1 < 64) ? __shfl(sA, i1, 64) : __shfl(sB, i1-64, 64);
      int s2 = (i2 < 64) ? __shfl(sA, i2, 64) : __shfl(sB, i2-64, 64);
      int s3 = (i3 < 64) ? __shfl(sA, i3, 64) : __shfl(sB, i3-64, 64);
      float w0 = (i0 < 64) ? __shfl(wA, i0, 64) : __shfl(wB, i0-64, 64);
      float w1 = (i1 < 64) ? __shfl(wA, i1, 64) : __shfl(wB, i1-64, 64);
      float w2 = (i2 < 64) ? __shfl(wA, i2, 64) : __shfl(wB, i2-64, 64);
      float w3 = (i3 < 64) ? __shfl(wA, i3, 64) : __shfl(wB, i3-64, 64);
      float v0 = b2f(base[(size_t)s0*256]);
      float v1 = b2f(base[(size_t)s1*256]);
      float v2 = b2f(base[(size_t)s2*256]);
      float v3 = b2f(base[(size_t)s3*256]);
      acc += v0*w0 + v1*w1 + v2*w2 + v3*w3;
    }
    for (; idx < deg; ++idx){
      int s = (idx < 64) ? __shfl(sA, idx, 64) : __shfl(sB, idx-64, 64);
      float w = (idx < 64) ? __shfl(wA, idx, 64) : __shfl(wB, idx-64, 64);
      acc += b2f(base[(size_t)s*256]) * w;
    }
  } else {
    float m = -3.0e38f;
    for (int i = e0 + lane; i < e1; i += 64){
      int s = csrc[i];
      m = fmaxf(m, lrelu(a_s[s*NH + h] + adst));
    }
    m = wmax(m);
    float se = 0.f;
    for (int i = e0 + lane; i < e1; i += 64){
      int s = csrc[i];
      se += __expf(lrelu(a_s[s*NH + h] + adst) - m);
    }
    se = wsum(se);
    inv = 1.f / (se + 1e-16f);
    for (int i = e0; i < e1; ++i){
      int s = csrc[i];
      float w = __expf(lrelu(a_s[s*NH + h] + adst) - m);
      acc += b2f(base[(size_t)s*256]) * w;
    }
  }
  float o = acc*inv + bv;
  h1out[(size_t)n*256 + h*HD + lane] = lrelu(o);
}

__global__ __launch_bounds__(256) void k_gat2(const u16* __restrict__ h2b, const float* __restrict__ a_s,
                       const float* __restrict__ a_d, const int* __restrict__ off,
                       const int* __restrict__ csrc, const float* __restrict__ b2,
                       float* __restrict__ h2out){
  int wv = threadIdx.x >> 6, lane = threadIdx.x & 63;
  int n = blockIdx.x*4 + wv;      // wave == node
  if (n >= NN) return;
  int e0 = off[n], e1 = off[n+1], deg = e1 - e0;
  float adst = a_d[n];
  float acc = 0.f, inv;
  const u16* base = h2b + lane;
  if (deg <= MAXDEG){
    int sA = 0, sB = 0;
    float alA = -3.0e38f, alB = -3.0e38f;
    if (lane < deg){
      sA = csrc[e0 + lane];
      alA = lrelu(a_s[sA] + adst);
    }
    if (64 + lane < deg){
      sB = csrc[e0 + 64 + lane];
      alB = lrelu(a_s[sB] + adst);
    }
    float m = wmax(fmaxf(alA, alB));
    float wA = (lane < deg)      ? __expf(alA - m) : 0.f;
    float wB = (64 + lane < deg) ? __expf(alB - m) : 0.f;
    float se = wsum(wA + wB);
    inv = 1.f / (se + 1e-16f);
    int idx = 0;
    for (; idx + 4 <= deg; idx += 4){
      int i0 = idx, i1 = idx+1, i2 = idx+2, i3 = idx+3;
      int s0 = (i0 < 64) ? __shfl(sA, i0, 64) : __shfl(sB, i0-64, 64);
      int s1 = (i1 < 64) ? __shfl(sA, i1, 64) : __shfl(sB, i1-64, 64);
      int s2 = (i2 < 64) ? __shfl(sA, i2, 64) : __shfl(sB, i2-64, 64);
      int s3 = (i3 < 64) ? __shfl(sA, i3, 64) : __shfl(sB, i3-64, 64);
      float w0 = (i0 < 64) ? __shfl(wA, i0, 64) : __shfl(wB, i0-64, 64);
      float w1 = (i1 < 64) ? __shfl(wA, i1, 64) : __shfl(wB, i1-64, 64);
      float w2 = (i2 < 64) ? __shfl(wA, i2, 64) : __shfl(wB, i2-64, 64);
      float w3 = (i3 < 64) ? __shfl(wA, i3, 64) : __shfl(wB, i3-64, 64);
      float v0 = b2f(base[(size_t)s0*HD]);
      float v1 = b2f(base[(size_t)s1*HD]);
      float v2 = b2f(base[(size_t)s2*HD]);
      float v3 = b2f(base[(size_t)s3*HD]);
      acc += v0*w0 + v1*w1 + v2*w2 + v3*w3;
    }
    for (; idx < deg; ++idx){
      int s = (idx < 64) ? __shfl(sA, idx, 64) : __shfl(sB, idx-64, 64);
      float w = (idx < 64) ? __shfl(wA, idx, 64) : __shfl(wB, idx-64, 64);
      acc += b2f(base[(size_t)s*HD]) * w;
    }
  } else {
    float m = -3.0e38f;
    for (int i = e0 + lane; i < e1; i += 64){
      int s = csrc[i];
      m = fmaxf(m, lrelu(a_s[s] + adst));
    }
    m = wmax(m);
    float se = 0.f;
    for (int i = e0 + lane; i < e1; i += 64){
      int s = csrc[i];
      se += __expf(lrelu(a_s[s] + adst) - m);
    }
    se = wsum(se);
    inv = 1.f / (se + 1e-16f);
    for (int i = e0; i < e1; ++i){
      int s = csrc[i];
      acc += b2f(base[(size_t)s*HD]) * __expf(lrelu(a_s[s] + adst) - m);
    }
  }
  float o = acc*inv + b2[lane];
  h2out[(size_t)n*HD + lane] = lrelu(o);
}

// ---------- pooling ----------

__global__ void k_pool(const float* __restrict__ h2out, const int* __restrict__ batch,
                       float* __restrict__ gsum, unsigned* __restrict__ gmaxk, int* __restrict__ gcnt){
  __shared__ float ssum[NGR*HD];
  __shared__ unsigned smax[NGR*HD];
  __shared__ int scnt[NGR];
  int t = threadIdx.x;   // 256
  for (int i = t; i < NGR*HD; i += 256){ ssum[i] = 0.f; smax[i] = 0u; }
  if (t < NGR) scnt[t] = 0;
  __syncthreads();
  int wv = t >> 6, lane = t & 63;
  for (int n = blockIdx.x*4 + wv; n < NN; n += gridDim.x*4){
    int g = batch[n];
    float v = h2out[(size_t)n*HD + lane];
    atomicAdd(&ssum[g*HD + lane], v);
    atomicMax(&smax[g*HD + lane], f2key(v));
    if (lane == 0) atomicAdd(&scnt[g], 1);
  }
  __syncthreads();
  for (int i = t; i < NGR*HD; i += 256){
    atomicAdd(&gsum[i], ssum[i]);
    atomicMax(&gmaxk[i], smax[i]);
  }
  if (t < NGR) atomicAdd(&gcnt[t], scnt[t]);
}

// ---------- final MLP + log_softmax ----------

__global__ void k_final(const float* __restrict__ gsum, const unsigned* __restrict__ gmaxk,
                        const int* __restrict__ gcnt,
                        const float* __restrict__ Wf1, const float* __restrict__ bf1,
                        const float* __restrict__ Wf2, const float* __restrict__ bf2,
                        float* __restrict__ out){
  int g = blockIdx.x, t = threadIdx.x;  // 64 threads
  __shared__ float gv[HD];
  __shared__ float f1[32];
  __shared__ float lg[NCL];
  int c = gcnt[g];
  float dn = fmaxf((float)c, 1.f);
  float mean = gsum[g*HD + t] / dn;
  float mx = (c > 0) ? key2f(gmaxk[g*HD + t]) : 0.f;
  gv[t] = mean + mx;
  __syncthreads();
  if (t < 32){
    float a = bf1[t];
#pragma unroll
    for (int k = 0; k < HD; ++k) a += gv[k] * Wf1[k*32 + t];
    f1[t] = a > 0.f ? a : 0.f;
  }
  __syncthreads();
  if (t < NCL){
    float a = bf2[t];
#pragma unroll
    for (int k = 0; k < 32; ++k) a += f1[k] * Wf2[k*NCL + t];
    lg[t] = a;
  }
  __syncthreads();
  if (t < NCL){
    float m = lg[0];
#pragma unroll
    for (int i = 1; i < NCL; ++i) m = fmaxf(m, lg[i]);
    float s = 0.f;
#pragma unroll
    for (int i = 0; i < NCL; ++i) s += expf(lg[i] - m);
    out[g*NCL + t] = lg[t] - m - logf(s);
  }
}

extern "C" void kernel_launch(void* const* d_in, const int* in_sizes, int n_in,
                              void* d_out, int out_size, void* d_ws, size_t ws_size,
                              hipStream_t stream) {
  const float* x   = (const float*)d_in[0];
  const int*   ei  = (const int*)d_in[1];
  const int*   bat = (const int*)d_in[2];
  const float* Wp  = (const float*)d_in[3];
  const float* bp  = (const float*)d_in[4];
  const float* W1  = (const float*)d_in[5];
  const float* as1 = (const float*)d_in[6];
  const float* ad1 = (const float*)d_in[7];
  const float* b1  = (const float*)d_in[8];
  const float* W2  = (const float*)d_in[9];
  const float* as2 = (const float*)d_in[10];
  const float* ad2 = (const float*)d_in[11];
  const float* b2  = (const float*)d_in[12];
  const float* Wf1 = (const float*)d_in[13];
  const float* bf1 = (const float*)d_in[14];
  const float* Wf2 = (const float*)d_in[15];
  const float* bf2 = (const float*)d_in[16];
  float* out = (float*)d_out;

  char* base = (char*)d_ws;
  size_t o = 0;
  auto alloc = [&](size_t elems) -> char* {   // elems are 4-byte units
    char* p = base + o*4;
    o += (elems + 63) & ~(size_t)63;
    return p;
  };
  float* h0     = (float*)alloc(3200000);      // [NN,64] f32 (reused as h2b)
  u16*   h1b    = (u16*)alloc(6400000);        // [NN,256] bf16 (front reused as h2out f32)
  float* h1out  = (float*)alloc(12800000);     // [NN,256] f32
  float* a_s1   = (float*)alloc(200000);
  float* a_d1   = (float*)alloc(200000);
  float* a_s2   = (float*)alloc(50000);
  float* a_d2   = (float*)alloc(50000);
  int*   cnt    = (int*)alloc(50000);
  int*   off    = (int*)alloc(50001);
  int*   pos    = (int*)alloc(50000);
  int*   bsums  = (int*)alloc(256);
  int*   boffs  = (int*)alloc(256);
  int*   csrc   = (int*)alloc(850000);
  float* gsum   = (float*)alloc(NGR*HD);
  unsigned* gmaxk = (unsigned*)alloc(NGR*HD);
  int*   gcnt   = (int*)alloc(NGR);
  u16*   h2b    = (u16*)h0;      // reuse (h0 dead after k_feat1)
  float* h2out  = (float*)h1b;   // reuse (h1b dead after k_gat1)

  const int NB = (NN + 255) / 256;
  const int EB = (ET + 255) / 256;

  // CSR build
  hipMemsetAsync(cnt, 0, NN*sizeof(int), stream);
  k_hist<<<EB, 256, 0, stream>>>(ei, cnt);
  k_bsum<<<NB, 256, 0, stream>>>(cnt, bsums);
  k_boff<<<1, 256, 0, stream>>>(bsums, boffs, NB);
  k_off<<<NB, 256, 0, stream>>>(cnt, boffs, off, pos);
  k_scatter<<<EB, 256, 0, stream>>>(ei, pos, csrc);

  // dense front-end
  k_proj<<<(NN + P_NPB - 1)/P_NPB, 256, 0, stream>>>(x, Wp, bp, h0);
  k_feat1<<<(NN + F1_NPB - 1)/F1_NPB, 256, 0, stream>>>(h0, W1, as1, ad1, h1b, a_s1, a_d1);

  // GAT layer 1
  k_gat1<<<NN, 256, 0, stream>>>(h1b, a_s1, a_d1, off, csrc, b1, h1out);

  // GAT layer 2
  k_feat2<<<(NN + F2_NPB - 1)/F2_NPB, 256, 0, stream>>>(h1out, W2, as2, ad2, h2b, a_s2, a_d2);
  k_gat2<<<(NN + 3)/4, 256, 0, stream>>>(h2b, a_s2, a_d2, off, csrc, b2, h2out);

  // pooling
  hipMemsetAsync(gsum, 0, (NGR*HD*2 + 64)*sizeof(int), stream);
  k_pool<<<256, 256, 0, stream>>>(h2out, bat, gsum, gmaxk, gcnt);

  // head MLP + log_softmax
  k_final<<<NGR, 64, 0, stream>>>(gsum, gmaxk, gcnt, Wf1, bf1, Wf2, bf2, out);
}

// Round 4
// 692.751 us; speedup vs baseline: 1.0158x; 1.0158x over previous
//
#include <hip/hip_runtime.h>
#include <math.h>

#define NN 50000
#define EE 800000
#define ET 850000    // EE + NN self loops
#define FIN 128
#define HD 64
#define NH 4
#define NGR 64
#define NCL 10
#define NEG 0.2f
#define MAXDEG 128

typedef unsigned short u16;
typedef unsigned int u32;

__device__ __forceinline__ float lrelu(float x){ return x > 0.f ? x : NEG * x; }

__device__ __forceinline__ float wsum(float v){
#pragma unroll
  for (int o = 32; o > 0; o >>= 1) v += __shfl_xor(v, o, 64);
  return v;
}
__device__ __forceinline__ float wmax(float v){
#pragma unroll
  for (int o = 32; o > 0; o >>= 1) v = fmaxf(v, __shfl_xor(v, o, 64));
  return v;
}
__device__ __forceinline__ int esrc(const int* ei, int e){ return e < EE ? ei[e] : e - EE; }
__device__ __forceinline__ int edst(const int* ei, int e){ return e < EE ? ei[EE + e] : e - EE; }

__device__ __forceinline__ unsigned f2key(float f){
  unsigned u = __float_as_uint(f);
  return (u & 0x80000000u) ? ~u : (u | 0x80000000u);
}
__device__ __forceinline__ float key2f(unsigned k){
  return (k & 0x80000000u) ? __uint_as_float(k & 0x7fffffffu) : __uint_as_float(~k);
}

// bf16 pack (RNE) / unpack
__device__ __forceinline__ u16 f2b(float f){
  u32 u = __float_as_uint(f);
  u32 r = (u + 0x7FFFu + ((u >> 16) & 1u)) >> 16;
  return (u16)r;
}
__device__ __forceinline__ float b2f(u16 b){ return __uint_as_float(((u32)b) << 16); }

// wave-uniform register broadcast (lane literal after full unroll)
__device__ __forceinline__ float rlane(float v, int l){
  return __uint_as_float(__builtin_amdgcn_readlane(__float_as_uint(v), l));
}

// ---------- dense kernels: W in LDS (per-lane reads), x in per-lane regs + readlane ----------
// Each WAVE owns 8 nodes per iteration; no cross-wave reduction.

#define P_ITERS 4     // 128 nodes/block
// h0 = relu(x @ W_proj + b_proj)   [NN,128]@[128,64]
__global__ __launch_bounds__(256) void k_proj(const float* __restrict__ x, const float* __restrict__ Wp,
                       const float* __restrict__ bp, float* __restrict__ h0){
  __shared__ float Ws[FIN*HD];     // 32KB
  int t = threadIdx.x, w = t >> 6, lane = t & 63;
  for (int i = t; i < FIN*HD; i += 256) Ws[i] = Wp[i];
  float bj = bp[lane];
  __syncthreads();
  for (int it = 0; it < P_ITERS; ++it){
    int nb = (blockIdx.x*P_ITERS + it)*32 + w*8;   // this wave's 8 nodes
    if (nb >= NN) break;
    float xq[8][2];
#pragma unroll
    for (int q = 0; q < 8; ++q){
      int n = nb + q;
      xq[q][0] = (n < NN) ? x[(size_t)n*FIN + lane]      : 0.f;
      xq[q][1] = (n < NN) ? x[(size_t)n*FIN + 64 + lane] : 0.f;
    }
    float acc[8];
#pragma unroll
    for (int q = 0; q < 8; ++q) acc[q] = 0.f;
#pragma unroll
    for (int r = 0; r < 2; ++r){
#pragma unroll
      for (int kk = 0; kk < 64; ++kk){
        float wv = Ws[(r*64 + kk)*HD + lane];
#pragma unroll
        for (int q = 0; q < 8; ++q) acc[q] = fmaf(rlane(xq[q][r], kk), wv, acc[q]);
      }
    }
#pragma unroll
    for (int q = 0; q < 8; ++q){
      int n = nb + q;
      if (n < NN) h0[(size_t)n*HD + lane] = fmaxf(acc[q] + bj, 0.f);
    }
  }
}

#define F1_ITERS 2    // 64 nodes/block
// h1b = bf16(h0 @ W1) [NN,64]@[64,256]; a_s1/a_d1 f32 dots. thread t = col t (head = t>>6).
__global__ __launch_bounds__(256) void k_feat1(const float* __restrict__ h0, const float* __restrict__ W1,
                        const float* __restrict__ as, const float* __restrict__ ad,
                        u16* __restrict__ h1b, float* __restrict__ a_s, float* __restrict__ a_d){
  __shared__ float Ws[HD*256];     // 64KB
  int t = threadIdx.x, w = t >> 6, lane = t & 63;
  for (int i = t; i < HD*256; i += 256) Ws[i] = W1[i];
  float asj = as[t], adj = ad[t];
  __syncthreads();
  for (int it = 0; it < F1_ITERS; ++it){
    int nb = (blockIdx.x*F1_ITERS + it)*32 + w*8;
    if (nb >= NN) break;
    float xq[8];
#pragma unroll
    for (int q = 0; q < 8; ++q){
      int n = nb + q;
      xq[q] = (n < NN) ? h0[(size_t)n*HD + lane] : 0.f;
    }
    float acc[8];
#pragma unroll
    for (int q = 0; q < 8; ++q) acc[q] = 0.f;
#pragma unroll
    for (int kk = 0; kk < 64; ++kk){
      float wv = Ws[kk*256 + t];
#pragma unroll
      for (int q = 0; q < 8; ++q) acc[q] = fmaf(rlane(xq[q], kk), wv, acc[q]);
    }
#pragma unroll
    for (int q = 0; q < 8; ++q){
      int n = nb + q;
      if (n < NN){
        h1b[(size_t)n*256 + t] = f2b(acc[q]);
        float vs = wsum(acc[q] * asj);
        float vd = wsum(acc[q] * adj);
        if (lane == 0){ a_s[n*NH + w] = vs; a_d[n*NH + w] = vd; }
      }
    }
  }
}

#define F2_ITERS 2    // 64 nodes/block
// h2b = bf16(h1out @ W2) [NN,256]@[256,64]; a_s2/a_d2 dots. lane = output col.
__global__ __launch_bounds__(256) void k_feat2(const float* __restrict__ h1out, const float* __restrict__ W2,
                        const float* __restrict__ as, const float* __restrict__ ad,
                        u16* __restrict__ h2b, float* __restrict__ a_s, float* __restrict__ a_d){
  __shared__ float Ws[256*HD];     // 64KB
  int t = threadIdx.x, w = t >> 6, lane = t & 63;
  for (int i = t; i < 256*HD; i += 256) Ws[i] = W2[i];
  float asl = as[lane], adl = ad[lane];
  __syncthreads();
  for (int it = 0; it < F2_ITERS; ++it){
    int nb = (blockIdx.x*F2_ITERS + it)*32 + w*8;
    if (nb >= NN) break;
    float xq[8][4];
#pragma unroll
    for (int q = 0; q < 8; ++q){
      int n = nb + q;
#pragma unroll
      for (int r = 0; r < 4; ++r)
        xq[q][r] = (n < NN) ? h1out[(size_t)n*256 + r*64 + lane] : 0.f;
    }
    float acc[8];
#pragma unroll
    for (int q = 0; q < 8; ++q) acc[q] = 0.f;
#pragma unroll
    for (int r = 0; r < 4; ++r){
#pragma unroll
      for (int kk = 0; kk < 64; ++kk){
        float wv = Ws[(r*64 + kk)*HD + lane];
#pragma unroll
        for (int q = 0; q < 8; ++q) acc[q] = fmaf(rlane(xq[q][r], kk), wv, acc[q]);
      }
    }
#pragma unroll
    for (int q = 0; q < 8; ++q){
      int n = nb + q;
      if (n < NN){
        float v = acc[q];
        float vs = wsum(v * asl);
        float vd = wsum(v * adl);
        h2b[(size_t)n*HD + lane] = f2b(v);
        if (lane == 0){ a_s[n] = vs; a_d[n] = vd; }
      }
    }
  }
}

// ---------- CSR build ----------

__global__ void k_hist(const int* __restrict__ ei, int* __restrict__ cnt){
  int e = blockIdx.x*256 + threadIdx.x;
  if (e < ET) atomicAdd(&cnt[edst(ei, e)], 1);
}

__global__ void k_bsum(const int* __restrict__ cnt, int* __restrict__ bsums){
  int b = blockIdx.x, t = threadIdx.x;
  int i = b*256 + t;
  int v = (i < NN) ? cnt[i] : 0;
  float s = wsum((float)v);
  __shared__ float ws4[4];
  if ((t & 63) == 0) ws4[t >> 6] = s;
  __syncthreads();
  if (t == 0) bsums[b] = (int)(ws4[0] + ws4[1] + ws4[2] + ws4[3] + 0.5f);
}

__global__ void k_boff(const int* __restrict__ bsums, int* __restrict__ boffs, int nb){
  __shared__ int s[256];
  int t = threadIdx.x;
  int v = (t < nb) ? bsums[t] : 0;
  s[t] = v; __syncthreads();
  for (int d = 1; d < 256; d <<= 1){
    int xv = (t >= d) ? s[t-d] : 0;
    __syncthreads();
    s[t] += xv;
    __syncthreads();
  }
  if (t < nb) boffs[t] = s[t] - v;
}

__global__ void k_off(const int* __restrict__ cnt, const int* __restrict__ boffs,
                      int* __restrict__ off, int* __restrict__ pos){
  int b = blockIdx.x, t = threadIdx.x;
  int i = b*256 + t;
  __shared__ int s[256];
  int v = (i < NN) ? cnt[i] : 0;
  s[t] = v; __syncthreads();
  for (int d = 1; d < 256; d <<= 1){
    int xv = (t >= d) ? s[t-d] : 0;
    __syncthreads();
    s[t] += xv;
    __syncthreads();
  }
  int excl = s[t] - v;
  if (i < NN){ int o = boffs[b] + excl; off[i] = o; pos[i] = o; }
  if (i == NN - 1) off[NN] = boffs[b] + s[t];
}

__global__ void k_scatter(const int* __restrict__ ei, int* __restrict__ pos, int* __restrict__ csrc){
  int e = blockIdx.x*256 + threadIdx.x;
  if (e < ET){
    int d = edst(ei, e);
    int idx = atomicAdd(&pos[d], 1);
    csrc[idx] = esrc(ei, e);
  }
}

// ---------- GAT aggregation (bf16 payload gather) ----------

__global__ __launch_bounds__(256) void k_gat1(const u16* __restrict__ h1b, const float* __restrict__ a_s,
                       const float* __restrict__ a_d, const int* __restrict__ off,
                       const int* __restrict__ csrc, const float* __restrict__ b1,
                       float* __restrict__ h1out){
  int n = blockIdx.x;
  int h = threadIdx.x >> 6, lane = threadIdx.x & 63;   // wave == head
  int e0 = off[n], e1 = off[n+1], deg = e1 - e0;
  float adst = a_d[n*NH + h];
  float bv = b1[h*HD + lane];
  float acc = 0.f, inv;
  const u16* base = h1b + h*HD + lane;
  if (deg <= MAXDEG){
    int sA = 0, sB = 0;
    float alA = -3.0e38f, alB = -3.0e38f;
    if (lane < deg){
      sA = csrc[e0 + lane];
      alA = lrelu(a_s[sA*NH + h] + adst);
    }
    if (64 + lane < deg){
      sB = csrc[e0 + 64 + lane];
      alB = lrelu(a_s[sB*NH + h] + adst);
    }
    float m = wmax(fmaxf(alA, alB));
    float wA = (lane < deg)      ? __expf(alA - m) : 0.f;
    float wB = (64 + lane < deg) ? __expf(alB - m) : 0.f;
    float se = wsum(wA + wB);
    inv = 1.f / (se + 1e-16f);
    int idx = 0;
    for (; idx + 4 <= deg; idx += 4){
      int i0 = idx, i1 = idx+1, i2 = idx+2, i3 = idx+3;
      int s0 = (i0 < 64) ? __shfl(sA, i0, 64) : __shfl(sB, i0-64, 64);
      int s1 = (i1 < 64) ? __shfl(sA, i1, 64) : __shfl(sB, i1-64, 64);
      int s2 = (i2 < 64) ? __shfl(sA, i2, 64) : __shfl(sB, i2-64, 64);
      int s3 = (i3 < 64) ? __shfl(sA, i3, 64) : __shfl(sB, i3-64, 64);
      float w0 = (i0 < 64) ? __shfl(wA, i0, 64) : __shfl(wB, i0-64, 64);
      float w1 = (i1 < 64) ? __shfl(wA, i1, 64) : __shfl(wB, i1-64, 64);
      float w2 = (i2 < 64) ? __shfl(wA, i2, 64) : __shfl(wB, i2-64, 64);
      float w3 = (i3 < 64) ? __shfl(wA, i3, 64) : __shfl(wB, i3-64, 64);
      float v0 = b2f(base[(size_t)s0*256]);
      float v1 = b2f(base[(size_t)s1*256]);
      float v2 = b2f(base[(size_t)s2*256]);
      float v3 = b2f(base[(size_t)s3*256]);
      acc += v0*w0 + v1*w1 + v2*w2 + v3*w3;
    }
    for (; idx < deg; ++idx){
      int s = (idx < 64) ? __shfl(sA, idx, 64) : __shfl(sB, idx-64, 64);
      float w = (idx < 64) ? __shfl(wA, idx, 64) : __shfl(wB, idx-64, 64);
      acc += b2f(base[(size_t)s*256]) * w;
    }
  } else {
    float m = -3.0e38f;
    for (int i = e0 + lane; i < e1; i += 64){
      int s = csrc[i];
      m = fmaxf(m, lrelu(a_s[s*NH + h] + adst));
    }
    m = wmax(m);
    float se = 0.f;
    for (int i = e0 + lane; i < e1; i += 64){
      int s = csrc[i];
      se += __expf(lrelu(a_s[s*NH + h] + adst) - m);
    }
    se = wsum(se);
    inv = 1.f / (se + 1e-16f);
    for (int i = e0; i < e1; ++i){
      int s = csrc[i];
      float w = __expf(lrelu(a_s[s*NH + h] + adst) - m);
      acc += b2f(base[(size_t)s*256]) * w;
    }
  }
  float o = acc*inv + bv;
  h1out[(size_t)n*256 + h*HD + lane] = lrelu(o);
}

__global__ __launch_bounds__(256) void k_gat2(const u16* __restrict__ h2b, const float* __restrict__ a_s,
                       const float* __restrict__ a_d, const int* __restrict__ off,
                       const int* __restrict__ csrc, const float* __restrict__ b2,
                       float* __restrict__ h2out){
  int wv = threadIdx.x >> 6, lane = threadIdx.x & 63;
  int n = blockIdx.x*4 + wv;      // wave == node
  if (n >= NN) return;
  int e0 = off[n], e1 = off[n+1], deg = e1 - e0;
  float adst = a_d[n];
  float acc = 0.f, inv;
  const u16* base = h2b + lane;
  if (deg <= MAXDEG){
    int sA = 0, sB = 0;
    float alA = -3.0e38f, alB = -3.0e38f;
    if (lane < deg){
      sA = csrc[e0 + lane];
      alA = lrelu(a_s[sA] + adst);
    }
    if (64 + lane < deg){
      sB = csrc[e0 + 64 + lane];
      alB = lrelu(a_s[sB] + adst);
    }
    float m = wmax(fmaxf(alA, alB));
    float wA = (lane < deg)      ? __expf(alA - m) : 0.f;
    float wB = (64 + lane < deg) ? __expf(alB - m) : 0.f;
    float se = wsum(wA + wB);
    inv = 1.f / (se + 1e-16f);
    int idx = 0;
    for (; idx + 4 <= deg; idx += 4){
      int i0 = idx, i1 = idx+1, i2 = idx+2, i3 = idx+3;
      int s0 = (i0 < 64) ? __shfl(sA, i0, 64) : __shfl(sB, i0-64, 64);
      int s1 = (i1 < 64) ? __shfl(sA, i1, 64) : __shfl(sB, i1-64, 64);
      int s2 = (i2 < 64) ? __shfl(sA, i2, 64) : __shfl(sB, i2-64, 64);
      int s3 = (i3 < 64) ? __shfl(sA, i3, 64) : __shfl(sB, i3-64, 64);
      float w0 = (i0 < 64) ? __shfl(wA, i0, 64) : __shfl(wB, i0-64, 64);
      float w1 = (i1 < 64) ? __shfl(wA, i1, 64) : __shfl(wB, i1-64, 64);
      float w2 = (i2 < 64) ? __shfl(wA, i2, 64) : __shfl(wB, i2-64, 64);
      float w3 = (i3 < 64) ? __shfl(wA, i3, 64) : __shfl(wB, i3-64, 64);
      float v0 = b2f(base[(size_t)s0*HD]);
      float v1 = b2f(base[(size_t)s1*HD]);
      float v2 = b2f(base[(size_t)s2*HD]);
      float v3 = b2f(base[(size_t)s3*HD]);
      acc += v0*w0 + v1*w1 + v2*w2 + v3*w3;
    }
    for (; idx < deg; ++idx){
      int s = (idx < 64) ? __shfl(sA, idx, 64) : __shfl(sB, idx-64, 64);
      float w = (idx < 64) ? __shfl(wA, idx, 64) : __shfl(wB, idx-64, 64);
      acc += b2f(base[(size_t)s*HD]) * w;
    }
  } else {
    float m = -3.0e38f;
    for (int i = e0 + lane; i < e1; i += 64){
      int s = csrc[i];
      m = fmaxf(m, lrelu(a_s[s] + adst));
    }
    m = wmax(m);
    float se = 0.f;
    for (int i = e0 + lane; i < e1; i += 64){
      int s = csrc[i];
      se += __expf(lrelu(a_s[s] + adst) - m);
    }
    se = wsum(se);
    inv = 1.f / (se + 1e-16f);
    for (int i = e0; i < e1; ++i){
      int s = csrc[i];
      acc += b2f(base[(size_t)s*HD]) * __expf(lrelu(a_s[s] + adst) - m);
    }
  }
  float o = acc*inv + b2[lane];
  h2out[(size_t)n*HD + lane] = lrelu(o);
}

// ---------- pooling ----------

__global__ void k_pool(const float* __restrict__ h2out, const int* __restrict__ batch,
                       float* __restrict__ gsum, unsigned* __restrict__ gmaxk, int* __restrict__ gcnt){
  __shared__ float ssum[NGR*HD];
  __shared__ unsigned smax[NGR*HD];
  __shared__ int scnt[NGR];
  int t = threadIdx.x;   // 256
  for (int i = t; i < NGR*HD; i += 256){ ssum[i] = 0.f; smax[i] = 0u; }
  if (t < NGR) scnt[t] = 0;
  __syncthreads();
  int wv = t >> 6, lane = t & 63;
  for (int n = blockIdx.x*4 + wv; n < NN; n += gridDim.x*4){
    int g = batch[n];
    float v = h2out[(size_t)n*HD + lane];
    atomicAdd(&ssum[g*HD + lane], v);
    atomicMax(&smax[g*HD + lane], f2key(v));
    if (lane == 0) atomicAdd(&scnt[g], 1);
  }
  __syncthreads();
  for (int i = t; i < NGR*HD; i += 256){
    atomicAdd(&gsum[i], ssum[i]);
    atomicMax(&gmaxk[i], smax[i]);
  }
  if (t < NGR) atomicAdd(&gcnt[t], scnt[t]);
}

// ---------- final MLP + log_softmax ----------

__global__ void k_final(const float* __restrict__ gsum, const unsigned* __restrict__ gmaxk,
                        const int* __restrict__ gcnt,
                        const float* __restrict__ Wf1, const float* __restrict__ bf1,
                        const float* __restrict__ Wf2, const float* __restrict__ bf2,
                        float* __restrict__ out){
  int g = blockIdx.x, t = threadIdx.x;  // 64 threads
  __shared__ float gv[HD];
  __shared__ float f1[32];
  __shared__ float lg[NCL];
  int c = gcnt[g];
  float dn = fmaxf((float)c, 1.f);
  float mean = gsum[g*HD + t] / dn;
  float mx = (c > 0) ? key2f(gmaxk[g*HD + t]) : 0.f;
  gv[t] = mean + mx;
  __syncthreads();
  if (t < 32){
    float a = bf1[t];
#pragma unroll
    for (int k = 0; k < HD; ++k) a += gv[k] * Wf1[k*32 + t];
    f1[t] = a > 0.f ? a : 0.f;
  }
  __syncthreads();
  if (t < NCL){
    float a = bf2[t];
#pragma unroll
    for (int k = 0; k < 32; ++k) a += f1[k] * Wf2[k*NCL + t];
    lg[t] = a;
  }
  __syncthreads();
  if (t < NCL){
    float m = lg[0];
#pragma unroll
    for (int i = 1; i < NCL; ++i) m = fmaxf(m, lg[i]);
    float s = 0.f;
#pragma unroll
    for (int i = 0; i < NCL; ++i) s += expf(lg[i] - m);
    out[g*NCL + t] = lg[t] - m - logf(s);
  }
}

extern "C" void kernel_launch(void* const* d_in, const int* in_sizes, int n_in,
                              void* d_out, int out_size, void* d_ws, size_t ws_size,
                              hipStream_t stream) {
  const float* x   = (const float*)d_in[0];
  const int*   ei  = (const int*)d_in[1];
  const int*   bat = (const int*)d_in[2];
  const float* Wp  = (const float*)d_in[3];
  const float* bp  = (const float*)d_in[4];
  const float* W1  = (const float*)d_in[5];
  const float* as1 = (const float*)d_in[6];
  const float* ad1 = (const float*)d_in[7];
  const float* b1  = (const float*)d_in[8];
  const float* W2  = (const float*)d_in[9];
  const float* as2 = (const float*)d_in[10];
  const float* ad2 = (const float*)d_in[11];
  const float* b2  = (const float*)d_in[12];
  const float* Wf1 = (const float*)d_in[13];
  const float* bf1 = (const float*)d_in[14];
  const float* Wf2 = (const float*)d_in[15];
  const float* bf2 = (const float*)d_in[16];
  float* out = (float*)d_out;

  char* base = (char*)d_ws;
  size_t o = 0;
  auto alloc = [&](size_t elems) -> char* {   // elems are 4-byte units
    char* p = base + o*4;
    o += (elems + 63) & ~(size_t)63;
    return p;
  };
  float* h0     = (float*)alloc(3200000);      // [NN,64] f32 (reused as h2b)
  u16*   h1b    = (u16*)alloc(6400000);        // [NN,256] bf16 (front reused as h2out f32)
  float* h1out  = (float*)alloc(12800000);     // [NN,256] f32
  float* a_s1   = (float*)alloc(200000);
  float* a_d1   = (float*)alloc(200000);
  float* a_s2   = (float*)alloc(50000);
  float* a_d2   = (float*)alloc(50000);
  int*   cnt    = (int*)alloc(50000);
  int*   off    = (int*)alloc(50001);
  int*   pos    = (int*)alloc(50000);
  int*   bsums  = (int*)alloc(256);
  int*   boffs  = (int*)alloc(256);
  int*   csrc   = (int*)alloc(850000);
  float* gsum   = (float*)alloc(NGR*HD);
  unsigned* gmaxk = (unsigned*)alloc(NGR*HD);
  int*   gcnt   = (int*)alloc(NGR);
  u16*   h2b    = (u16*)h0;      // reuse (h0 dead after k_feat1)
  float* h2out  = (float*)h1b;   // reuse (h1b dead after k_gat1)

  const int NB = (NN + 255) / 256;
  const int EB = (ET + 255) / 256;

  // CSR build
  hipMemsetAsync(cnt, 0, NN*sizeof(int), stream);
  k_hist<<<EB, 256, 0, stream>>>(ei, cnt);
  k_bsum<<<NB, 256, 0, stream>>>(cnt, bsums);
  k_boff<<<1, 256, 0, stream>>>(bsums, boffs, NB);
  k_off<<<NB, 256, 0, stream>>>(cnt, boffs, off, pos);
  k_scatter<<<EB, 256, 0, stream>>>(ei, pos, csrc);

  // dense front-end
  k_proj<<<(NN + P_ITERS*32 - 1)/(P_ITERS*32), 256, 0, stream>>>(x, Wp, bp, h0);
  k_feat1<<<(NN + F1_ITERS*32 - 1)/(F1_ITERS*32), 256, 0, stream>>>(h0, W1, as1, ad1, h1b, a_s1, a_d1);

  // GAT layer 1
  k_gat1<<<NN, 256, 0, stream>>>(h1b, a_s1, a_d1, off, csrc, b1, h1out);

  // GAT layer 2
  k_feat2<<<(NN + F2_ITERS*32 - 1)/(F2_ITERS*32), 256, 0, stream>>>(h1out, W2, as2, ad2, h2b, a_s2, a_d2);
  k_gat2<<<(NN + 3)/4, 256, 0, stream>>>(h2b, a_s2, a_d2, off, csrc, b2, h2out);

  // pooling
  hipMemsetAsync(gsum, 0, (NGR*HD*2 + 64)*sizeof(int), stream);
  k_pool<<<256, 256, 0, stream>>>(h2out, bat, gsum, gmaxk, gcnt);

  // head MLP + log_softmax
  k_final<<<NGR, 64, 0, stream>>>(gsum, gmaxk, gcnt, Wf1, bf1, Wf2, bf2, out);
}

// Round 5
// 390.267 us; speedup vs baseline: 1.8032x; 1.7751x over previous
//
#include <hip/hip_runtime.h>
#include <math.h>

#define NN 50000
#define EE 800000
#define ET 850000    // EE + NN self loops
#define FIN 128
#define HD 64
#define NH 4
#define NGR 64
#define NCL 10
#define NEG 0.2f
#define MAXDEG 128

typedef unsigned short u16;
typedef unsigned int u32;
typedef __attribute__((ext_vector_type(8))) short short8;
typedef __attribute__((ext_vector_type(4))) float f32x4;

__device__ __forceinline__ float lrelu(float x){ return x > 0.f ? x : NEG * x; }

__device__ __forceinline__ float wsum(float v){
#pragma unroll
  for (int o = 32; o > 0; o >>= 1) v += __shfl_xor(v, o, 64);
  return v;
}
__device__ __forceinline__ float wmax(float v){
#pragma unroll
  for (int o = 32; o > 0; o >>= 1) v = fmaxf(v, __shfl_xor(v, o, 64));
  return v;
}
__device__ __forceinline__ int esrc(const int* ei, int e){ return e < EE ? ei[e] : e - EE; }
__device__ __forceinline__ int edst(const int* ei, int e){ return e < EE ? ei[EE + e] : e - EE; }

__device__ __forceinline__ unsigned f2key(float f){
  unsigned u = __float_as_uint(f);
  return (u & 0x80000000u) ? ~u : (u | 0x80000000u);
}
__device__ __forceinline__ float key2f(unsigned k){
  return (k & 0x80000000u) ? __uint_as_float(k & 0x7fffffffu) : __uint_as_float(~k);
}

// bf16 pack (RNE) / unpack
__device__ __forceinline__ u16 f2b(float f){
  u32 u = __float_as_uint(f);
  u32 r = (u + 0x7FFFu + ((u >> 16) & 1u)) >> 16;
  return (u16)r;
}
__device__ __forceinline__ float b2f(u16 b){ return __uint_as_float(((u32)b) << 16); }

// ---------- cast inputs to bf16 ----------
__global__ __launch_bounds__(256) void k_cast(const float* __restrict__ x, const float* __restrict__ Wp,
                       const float* __restrict__ W1, const float* __restrict__ W2,
                       u16* __restrict__ xb, u16* __restrict__ Wpb, u16* __restrict__ W1b, u16* __restrict__ W2b){
  int b = blockIdx.x, t = threadIdx.x;
  if (b < 6250){
    size_t i = ((size_t)b*256 + t)*4;
    float4 v = *(const float4*)&x[i];
    ushort4 o;
    o.x = f2b(v.x); o.y = f2b(v.y); o.z = f2b(v.z); o.w = f2b(v.w);
    *(ushort4*)&xb[i] = o;
  } else {
    for (int i = t; i < FIN*HD; i += 256) Wpb[i] = f2b(Wp[i]);
    for (int i = t; i < HD*256; i += 256) W1b[i] = f2b(W1[i]);
    for (int i = t; i < 256*HD; i += 256) W2b[i] = f2b(W2[i]);
  }
}

// ---------- MFMA GEMM: C[M,NOUT] = A[M,K] @ B[K,NOUT], bf16 in, bf16 out ----------
// 256 thr = 4 waves; wave w owns cols [w*CPW, w*CPW+CPW). 2 chunks of 64 rows per block.
// A/B frag: idx=lane&15, k=(lane>>4)*8+j.  C/D: col=lane&15, row=(lane>>4)*4+reg.
template<int K, int NOUT, int CPW, bool RELU_BIAS, bool DOTS>
__global__ __launch_bounds__(256) void k_gemm(const u16* __restrict__ A, const u16* __restrict__ B,
            const float* __restrict__ bias, const float* __restrict__ att_s, const float* __restrict__ att_d,
            u16* __restrict__ C, float* __restrict__ a_s, float* __restrict__ a_d){
  constexpr int KT = K/32;
  constexpr int NT = CPW/16;
  constexpr int LDK = K + 8;          // +16B pad -> bank stride 4
  __shared__ u16 As[64*LDK];
  int t = threadIdx.x, w = t >> 6, l = t & 63;
  int c0 = w*CPW;
  int l16 = l & 15, kg = l >> 4;

  // B fragments (registers, loaded once)
  short8 bf[KT*NT];
#pragma unroll
  for (int kt = 0; kt < KT; ++kt)
#pragma unroll
    for (int nt = 0; nt < NT; ++nt){
      int kbase = kt*32 + kg*8;
      int col = c0 + nt*16 + l16;
      short8 v;
#pragma unroll
      for (int j = 0; j < 8; ++j) v[j] = (short)B[(size_t)(kbase + j)*NOUT + col];
      bf[kt*NT + nt] = v;
    }
  float bv = 0.f;
  if (RELU_BIAS) bv = bias[c0 + l16];
  float asv[NT], adv[NT];
  if (DOTS){
#pragma unroll
    for (int nt = 0; nt < NT; ++nt){
      asv[nt] = att_s[c0 + nt*16 + l16];
      adv[nt] = att_d[c0 + nt*16 + l16];
    }
  }

  for (int ch = 0; ch < 2; ++ch){
    int nb = (blockIdx.x*2 + ch)*64;
    if (nb >= NN) break;
    __syncthreads();
    // stage A chunk (64 rows) into padded LDS
    constexpr int UPR = K/8;   // 16B units per row
    for (int u = t; u < 64*UPR; u += 256){
      int r = u / UPR, c = u % UPR;
      int n = nb + r;
      uint4 v = make_uint4(0u,0u,0u,0u);
      if (n < NN) v = *(const uint4*)&A[(size_t)n*K + c*8];
      *(uint4*)&As[r*LDK + c*8] = v;
    }
    __syncthreads();
#pragma unroll
    for (int rt = 0; rt < 4; ++rt){
      short8 af[KT];
#pragma unroll
      for (int kt = 0; kt < KT; ++kt)
        af[kt] = *(const short8*)&As[(rt*16 + l16)*LDK + kt*32 + kg*8];
      f32x4 acc[NT];
#pragma unroll
      for (int nt = 0; nt < NT; ++nt){
        acc[nt] = (f32x4){0.f,0.f,0.f,0.f};
#pragma unroll
        for (int kt = 0; kt < KT; ++kt)
          acc[nt] = __builtin_amdgcn_mfma_f32_16x16x32_bf16(af[kt], bf[kt*NT + nt], acc[nt], 0, 0, 0);
      }
      int rbase = nb + rt*16 + kg*4;
      // store C
#pragma unroll
      for (int nt = 0; nt < NT; ++nt)
#pragma unroll
        for (int r4 = 0; r4 < 4; ++r4){
          int n = rbase + r4;
          if (n < NN){
            float v = acc[nt][r4];
            if (RELU_BIAS) v = fmaxf(v + bv, 0.f);
            C[(size_t)n*NOUT + c0 + nt*16 + l16] = f2b(v);
          }
        }
      if (DOTS){
        // head == wave (CPW=64): per-row dot over this wave's 64 cols, f32 acc
#pragma unroll
        for (int r4 = 0; r4 < 4; ++r4){
          float ps = 0.f, pd = 0.f;
#pragma unroll
          for (int nt = 0; nt < NT; ++nt){
            ps = fmaf(acc[nt][r4], asv[nt], ps);
            pd = fmaf(acc[nt][r4], adv[nt], pd);
          }
#pragma unroll
          for (int o = 1; o < 16; o <<= 1){
            ps += __shfl_xor(ps, o, 64);
            pd += __shfl_xor(pd, o, 64);
          }
          int n = rbase + r4;
          if (l16 == 0 && n < NN){ a_s[n*NH + w] = ps; a_d[n*NH + w] = pd; }
        }
      }
    }
  }
}

// ---------- CSR build ----------

__global__ void k_hist(const int* __restrict__ ei, int* __restrict__ cnt){
  int e = blockIdx.x*256 + threadIdx.x;
  if (e < ET) atomicAdd(&cnt[edst(ei, e)], 1);
}

__global__ void k_bsum(const int* __restrict__ cnt, int* __restrict__ bsums){
  int b = blockIdx.x, t = threadIdx.x;
  int i = b*256 + t;
  int v = (i < NN) ? cnt[i] : 0;
  float s = wsum((float)v);
  __shared__ float ws4[4];
  if ((t & 63) == 0) ws4[t >> 6] = s;
  __syncthreads();
  if (t == 0) bsums[b] = (int)(ws4[0] + ws4[1] + ws4[2] + ws4[3] + 0.5f);
}

__global__ void k_boff(const int* __restrict__ bsums, int* __restrict__ boffs, int nb){
  __shared__ int s[256];
  int t = threadIdx.x;
  int v = (t < nb) ? bsums[t] : 0;
  s[t] = v; __syncthreads();
  for (int d = 1; d < 256; d <<= 1){
    int xv = (t >= d) ? s[t-d] : 0;
    __syncthreads();
    s[t] += xv;
    __syncthreads();
  }
  if (t < nb) boffs[t] = s[t] - v;
}

__global__ void k_off(const int* __restrict__ cnt, const int* __restrict__ boffs,
                      int* __restrict__ off, int* __restrict__ pos){
  int b = blockIdx.x, t = threadIdx.x;
  int i = b*256 + t;
  __shared__ int s[256];
  int v = (i < NN) ? cnt[i] : 0;
  s[t] = v; __syncthreads();
  for (int d = 1; d < 256; d <<= 1){
    int xv = (t >= d) ? s[t-d] : 0;
    __syncthreads();
    s[t] += xv;
    __syncthreads();
  }
  int excl = s[t] - v;
  if (i < NN){ int o = boffs[b] + excl; off[i] = o; pos[i] = o; }
  if (i == NN - 1) off[NN] = boffs[b] + s[t];
}

__global__ void k_scatter(const int* __restrict__ ei, int* __restrict__ pos, int* __restrict__ csrc){
  int e = blockIdx.x*256 + threadIdx.x;
  if (e < ET){
    int d = edst(ei, e);
    int idx = atomicAdd(&pos[d], 1);
    csrc[idx] = esrc(ei, e);
  }
}

// ---------- GAT aggregation (bf16 payload gather) ----------

__global__ __launch_bounds__(256) void k_gat1(const u16* __restrict__ h1b, const float* __restrict__ a_s,
                       const float* __restrict__ a_d, const int* __restrict__ off,
                       const int* __restrict__ csrc, const float* __restrict__ b1,
                       u16* __restrict__ h1outb){
  int n = blockIdx.x;
  int h = threadIdx.x >> 6, lane = threadIdx.x & 63;   // wave == head
  int e0 = off[n], e1 = off[n+1], deg = e1 - e0;
  float adst = a_d[n*NH + h];
  float bv = b1[h*HD + lane];
  float acc = 0.f, inv;
  const u16* base = h1b + h*HD + lane;
  if (deg <= MAXDEG){
    int sA = 0, sB = 0;
    float alA = -3.0e38f, alB = -3.0e38f;
    if (lane < deg){
      sA = csrc[e0 + lane];
      alA = lrelu(a_s[sA*NH + h] + adst);
    }
    if (64 + lane < deg){
      sB = csrc[e0 + 64 + lane];
      alB = lrelu(a_s[sB*NH + h] + adst);
    }
    float m = wmax(fmaxf(alA, alB));
    float wA = (lane < deg)      ? __expf(alA - m) : 0.f;
    float wB = (64 + lane < deg) ? __expf(alB - m) : 0.f;
    float se = wsum(wA + wB);
    inv = 1.f / (se + 1e-16f);
    int idx = 0;
    for (; idx + 4 <= deg; idx += 4){
      int i0 = idx, i1 = idx+1, i2 = idx+2, i3 = idx+3;
      int s0 = (i0 < 64) ? __shfl(sA, i0, 64) : __shfl(sB, i0-64, 64);
      int s1 = (i1 < 64) ? __shfl(sA, i1, 64) : __shfl(sB, i1-64, 64);
      int s2 = (i2 < 64) ? __shfl(sA, i2, 64) : __shfl(sB, i2-64, 64);
      int s3 = (i3 < 64) ? __shfl(sA, i3, 64) : __shfl(sB, i3-64, 64);
      float w0 = (i0 < 64) ? __shfl(wA, i0, 64) : __shfl(wB, i0-64, 64);
      float w1 = (i1 < 64) ? __shfl(wA, i1, 64) : __shfl(wB, i1-64, 64);
      float w2 = (i2 < 64) ? __shfl(wA, i2, 64) : __shfl(wB, i2-64, 64);
      float w3 = (i3 < 64) ? __shfl(wA, i3, 64) : __shfl(wB, i3-64, 64);
      float v0 = b2f(base[(size_t)s0*256]);
      float v1 = b2f(base[(size_t)s1*256]);
      float v2 = b2f(base[(size_t)s2*256]);
      float v3 = b2f(base[(size_t)s3*256]);
      acc += v0*w0 + v1*w1 + v2*w2 + v3*w3;
    }
    for (; idx < deg; ++idx){
      int s = (idx < 64) ? __shfl(sA, idx, 64) : __shfl(sB, idx-64, 64);
      float w = (idx < 64) ? __shfl(wA, idx, 64) : __shfl(wB, idx-64, 64);
      acc += b2f(base[(size_t)s*256]) * w;
    }
  } else {
    float m = -3.0e38f;
    for (int i = e0 + lane; i < e1; i += 64){
      int s = csrc[i];
      m = fmaxf(m, lrelu(a_s[s*NH + h] + adst));
    }
    m = wmax(m);
    float se = 0.f;
    for (int i = e0 + lane; i < e1; i += 64){
      int s = csrc[i];
      se += __expf(lrelu(a_s[s*NH + h] + adst) - m);
    }
    se = wsum(se);
    inv = 1.f / (se + 1e-16f);
    for (int i = e0; i < e1; ++i){
      int s = csrc[i];
      float w = __expf(lrelu(a_s[s*NH + h] + adst) - m);
      acc += b2f(base[(size_t)s*256]) * w;
    }
  }
  float o = acc*inv + bv;
  h1outb[(size_t)n*256 + h*HD + lane] = f2b(lrelu(o));
}

// layer-2 attention dots from h2b
__global__ __launch_bounds__(256) void k_dots2(const u16* __restrict__ h2b, const float* __restrict__ as2,
                        const float* __restrict__ ad2, float* __restrict__ a_s, float* __restrict__ a_d){
  int w = threadIdx.x >> 6, l = threadIdx.x & 63;
  int n = blockIdx.x*4 + w;
  if (n >= NN) return;
  float v = b2f(h2b[(size_t)n*HD + l]);
  float s = wsum(v * as2[l]);
  float d = wsum(v * ad2[l]);
  if (l == 0){ a_s[n] = s; a_d[n] = d; }
}

__global__ __launch_bounds__(256) void k_gat2(const u16* __restrict__ h2b, const float* __restrict__ a_s,
                       const float* __restrict__ a_d, const int* __restrict__ off,
                       const int* __restrict__ csrc, const float* __restrict__ b2,
                       float* __restrict__ h2out){
  int wv = threadIdx.x >> 6, lane = threadIdx.x & 63;
  int n = blockIdx.x*4 + wv;      // wave == node
  if (n >= NN) return;
  int e0 = off[n], e1 = off[n+1], deg = e1 - e0;
  float adst = a_d[n];
  float acc = 0.f, inv;
  const u16* base = h2b + lane;
  if (deg <= MAXDEG){
    int sA = 0, sB = 0;
    float alA = -3.0e38f, alB = -3.0e38f;
    if (lane < deg){
      sA = csrc[e0 + lane];
      alA = lrelu(a_s[sA] + adst);
    }
    if (64 + lane < deg){
      sB = csrc[e0 + 64 + lane];
      alB = lrelu(a_s[sB] + adst);
    }
    float m = wmax(fmaxf(alA, alB));
    float wA = (lane < deg)      ? __expf(alA - m) : 0.f;
    float wB = (64 + lane < deg) ? __expf(alB - m) : 0.f;
    float se = wsum(wA + wB);
    inv = 1.f / (se + 1e-16f);
    int idx = 0;
    for (; idx + 4 <= deg; idx += 4){
      int i0 = idx, i1 = idx+1, i2 = idx+2, i3 = idx+3;
      int s0 = (i0 < 64) ? __shfl(sA, i0, 64) : __shfl(sB, i0-64, 64);
      int s1 = (i1 < 64) ? __shfl(sA, i1, 64) : __shfl(sB, i1-64, 64);
      int s2 = (i2 < 64) ? __shfl(sA, i2, 64) : __shfl(sB, i2-64, 64);
      int s3 = (i3 < 64) ? __shfl(sA, i3, 64) : __shfl(sB, i3-64, 64);
      float w0 = (i0 < 64) ? __shfl(wA, i0, 64) : __shfl(wB, i0-64, 64);
      float w1 = (i1 < 64) ? __shfl(wA, i1, 64) : __shfl(wB, i1-64, 64);
      float w2 = (i2 < 64) ? __shfl(wA, i2, 64) : __shfl(wB, i2-64, 64);
      float w3 = (i3 < 64) ? __shfl(wA, i3, 64) : __shfl(wB, i3-64, 64);
      float v0 = b2f(base[(size_t)s0*HD]);
      float v1 = b2f(base[(size_t)s1*HD]);
      float v2 = b2f(base[(size_t)s2*HD]);
      float v3 = b2f(base[(size_t)s3*HD]);
      acc += v0*w0 + v1*w1 + v2*w2 + v3*w3;
    }
    for (; idx < deg; ++idx){
      int s = (idx < 64) ? __shfl(sA, idx, 64) : __shfl(sB, idx-64, 64);
      float w = (idx < 64) ? __shfl(wA, idx, 64) : __shfl(wB, idx-64, 64);
      acc += b2f(base[(size_t)s*HD]) * w;
    }
  } else {
    float m = -3.0e38f;
    for (int i = e0 + lane; i < e1; i += 64){
      int s = csrc[i];
      m = fmaxf(m, lrelu(a_s[s] + adst));
    }
    m = wmax(m);
    float se = 0.f;
    for (int i = e0 + lane; i < e1; i += 64){
      int s = csrc[i];
      se += __expf(lrelu(a_s[s] + adst) - m);
    }
    se = wsum(se);
    inv = 1.f / (se + 1e-16f);
    for (int i = e0; i < e1; ++i){
      int s = csrc[i];
      acc += b2f(base[(size_t)s*HD]) * __expf(lrelu(a_s[s] + adst) - m);
    }
  }
  float o = acc*inv + b2[lane];
  h2out[(size_t)n*HD + lane] = lrelu(o);
}

// ---------- pooling ----------

__global__ void k_pool(const float* __restrict__ h2out, const int* __restrict__ batch,
                       float* __restrict__ gsum, unsigned* __restrict__ gmaxk, int* __restrict__ gcnt){
  __shared__ float ssum[NGR*HD];
  __shared__ unsigned smax[NGR*HD];
  __shared__ int scnt[NGR];
  int t = threadIdx.x;   // 256
  for (int i = t; i < NGR*HD; i += 256){ ssum[i] = 0.f; smax[i] = 0u; }
  if (t < NGR) scnt[t] = 0;
  __syncthreads();
  int wv = t >> 6, lane = t & 63;
  for (int n = blockIdx.x*4 + wv; n < NN; n += gridDim.x*4){
    int g = batch[n];
    float v = h2out[(size_t)n*HD + lane];
    atomicAdd(&ssum[g*HD + lane], v);
    atomicMax(&smax[g*HD + lane], f2key(v));
    if (lane == 0) atomicAdd(&scnt[g], 1);
  }
  __syncthreads();
  for (int i = t; i < NGR*HD; i += 256){
    atomicAdd(&gsum[i], ssum[i]);
    atomicMax(&gmaxk[i], smax[i]);
  }
  if (t < NGR) atomicAdd(&gcnt[t], scnt[t]);
}

// ---------- final MLP + log_softmax ----------

__global__ void k_final(const float* __restrict__ gsum, const unsigned* __restrict__ gmaxk,
                        const int* __restrict__ gcnt,
                        const float* __restrict__ Wf1, const float* __restrict__ bf1,
                        const float* __restrict__ Wf2, const float* __restrict__ bf2,
                        float* __restrict__ out){
  int g = blockIdx.x, t = threadIdx.x;  // 64 threads
  __shared__ float gv[HD];
  __shared__ float f1[32];
  __shared__ float lg[NCL];
  int c = gcnt[g];
  float dn = fmaxf((float)c, 1.f);
  float mean = gsum[g*HD + t] / dn;
  float mx = (c > 0) ? key2f(gmaxk[g*HD + t]) : 0.f;
  gv[t] = mean + mx;
  __syncthreads();
  if (t < 32){
    float a = bf1[t];
#pragma unroll
    for (int k = 0; k < HD; ++k) a += gv[k] * Wf1[k*32 + t];
    f1[t] = a > 0.f ? a : 0.f;
  }
  __syncthreads();
  if (t < NCL){
    float a = bf2[t];
#pragma unroll
    for (int k = 0; k < 32; ++k) a += f1[k] * Wf2[k*NCL + t];
    lg[t] = a;
  }
  __syncthreads();
  if (t < NCL){
    float m = lg[0];
#pragma unroll
    for (int i = 1; i < NCL; ++i) m = fmaxf(m, lg[i]);
    float s = 0.f;
#pragma unroll
    for (int i = 0; i < NCL; ++i) s += expf(lg[i] - m);
    out[g*NCL + t] = lg[t] - m - logf(s);
  }
}

extern "C" void kernel_launch(void* const* d_in, const int* in_sizes, int n_in,
                              void* d_out, int out_size, void* d_ws, size_t ws_size,
                              hipStream_t stream) {
  const float* x   = (const float*)d_in[0];
  const int*   ei  = (const int*)d_in[1];
  const int*   bat = (const int*)d_in[2];
  const float* Wp  = (const float*)d_in[3];
  const float* bp  = (const float*)d_in[4];
  const float* W1  = (const float*)d_in[5];
  const float* as1 = (const float*)d_in[6];
  const float* ad1 = (const float*)d_in[7];
  const float* b1  = (const float*)d_in[8];
  const float* W2  = (const float*)d_in[9];
  const float* as2 = (const float*)d_in[10];
  const float* ad2 = (const float*)d_in[11];
  const float* b2  = (const float*)d_in[12];
  const float* Wf1 = (const float*)d_in[13];
  const float* bf1 = (const float*)d_in[14];
  const float* Wf2 = (const float*)d_in[15];
  const float* bf2 = (const float*)d_in[16];
  float* out = (float*)d_out;

  char* base = (char*)d_ws;
  size_t o = 0;
  auto alloc = [&](size_t elems) -> char* {   // elems are 4-byte units
    char* p = base + o*4;
    o += (elems + 63) & ~(size_t)63;
    return p;
  };
  u16*   xb     = (u16*)alloc(3200000);      // [NN,128] bf16
  u16*   Wpb    = (u16*)alloc(4096);         // [128,64]
  u16*   W1b    = (u16*)alloc(8192);         // [64,256]
  u16*   W2b    = (u16*)alloc(8192);         // [256,64]
  u16*   h0b    = (u16*)alloc(1600000);      // [NN,64] bf16
  u16*   h1b    = (u16*)alloc(6400000);      // [NN,256] bf16
  u16*   h1outb = (u16*)alloc(6400000);      // [NN,256] bf16
  u16*   h2b    = (u16*)alloc(800000);       // [NN,64] bf16
  float* h2out  = (float*)alloc(3200000);    // [NN,64] f32
  float* a_s1   = (float*)alloc(200000);
  float* a_d1   = (float*)alloc(200000);
  float* a_s2   = (float*)alloc(50000);
  float* a_d2   = (float*)alloc(50000);
  int*   cnt    = (int*)alloc(50000);
  int*   off    = (int*)alloc(50001);
  int*   pos    = (int*)alloc(50000);
  int*   bsums  = (int*)alloc(256);
  int*   boffs  = (int*)alloc(256);
  int*   csrc   = (int*)alloc(850000);
  float* gsum   = (float*)alloc(NGR*HD);
  unsigned* gmaxk = (unsigned*)alloc(NGR*HD);
  int*   gcnt   = (int*)alloc(NGR);

  const int NB = (NN + 255) / 256;
  const int EB = (ET + 255) / 256;
  const int GB = (NN + 127) / 128;    // gemm blocks (2x64 rows each)

  // CSR build
  hipMemsetAsync(cnt, 0, NN*sizeof(int), stream);
  k_hist<<<EB, 256, 0, stream>>>(ei, cnt);
  k_bsum<<<NB, 256, 0, stream>>>(cnt, bsums);
  k_boff<<<1, 256, 0, stream>>>(bsums, boffs, NB);
  k_off<<<NB, 256, 0, stream>>>(cnt, boffs, off, pos);
  k_scatter<<<EB, 256, 0, stream>>>(ei, pos, csrc);

  // cast to bf16
  k_cast<<<6251, 256, 0, stream>>>(x, Wp, W1, W2, xb, Wpb, W1b, W2b);

  // dense front-end (MFMA)
  k_gemm<128, 64, 16, true, false><<<GB, 256, 0, stream>>>(xb, Wpb, bp, nullptr, nullptr, h0b, nullptr, nullptr);
  k_gemm<64, 256, 64, false, true><<<GB, 256, 0, stream>>>(h0b, W1b, nullptr, as1, ad1, h1b, a_s1, a_d1);

  // GAT layer 1
  k_gat1<<<NN, 256, 0, stream>>>(h1b, a_s1, a_d1, off, csrc, b1, h1outb);

  // GAT layer 2
  k_gemm<256, 64, 16, false, false><<<GB, 256, 0, stream>>>(h1outb, W2b, nullptr, nullptr, nullptr, h2b, nullptr, nullptr);
  k_dots2<<<(NN + 3)/4, 256, 0, stream>>>(h2b, as2, ad2, a_s2, a_d2);
  k_gat2<<<(NN + 3)/4, 256, 0, stream>>>(h2b, a_s2, a_d2, off, csrc, b2, h2out);

  // pooling
  hipMemsetAsync(gsum, 0, (NGR*HD*2 + 64)*sizeof(int), stream);
  k_pool<<<256, 256, 0, stream>>>(h2out, bat, gsum, gmaxk, gcnt);

  // head MLP + log_softmax
  k_final<<<NGR, 64, 0, stream>>>(gsum, gmaxk, gcnt, Wf1, bf1, Wf2, bf2, out);
}

// Round 6
// 301.455 us; speedup vs baseline: 2.3344x; 1.2946x over previous
//
#include <hip/hip_runtime.h>
#include <math.h>

#define NN 50000
#define EE 800000
#define ET 850000    // EE + NN self loops
#define FIN 128
#define HD 64
#define NH 4
#define NGR 64
#define NCL 10
#define NEG 0.2f

typedef unsigned short u16;
typedef unsigned int u32;
typedef __attribute__((ext_vector_type(8))) short short8;
typedef __attribute__((ext_vector_type(4))) float f32x4;

__device__ __forceinline__ float lrelu(float x){ return x > 0.f ? x : NEG * x; }

__device__ __forceinline__ float wsum(float v){
#pragma unroll
  for (int o = 32; o > 0; o >>= 1) v += __shfl_xor(v, o, 64);
  return v;
}
__device__ __forceinline__ float wmax(float v){
#pragma unroll
  for (int o = 32; o > 0; o >>= 1) v = fmaxf(v, __shfl_xor(v, o, 64));
  return v;
}
__device__ __forceinline__ int esrc(const int* ei, int e){ return e < EE ? ei[e] : e - EE; }
__device__ __forceinline__ int edst(const int* ei, int e){ return e < EE ? ei[EE + e] : e - EE; }

__device__ __forceinline__ unsigned f2key(float f){
  unsigned u = __float_as_uint(f);
  return (u & 0x80000000u) ? ~u : (u | 0x80000000u);
}
__device__ __forceinline__ float key2f(unsigned k){
  return (k & 0x80000000u) ? __uint_as_float(k & 0x7fffffffu) : __uint_as_float(~k);
}

// bf16 pack (RNE) / unpack
__device__ __forceinline__ u16 f2b(float f){
  u32 u = __float_as_uint(f);
  u32 r = (u + 0x7FFFu + ((u >> 16) & 1u)) >> 16;
  return (u16)r;
}
__device__ __forceinline__ float b2f(u16 b){ return __uint_as_float(((u32)b) << 16); }
__device__ __forceinline__ u32 pkbf16(float lo, float hi){
  u32 r;
  asm("v_cvt_pk_bf16_f32 %0, %1, %2" : "=v"(r) : "v"(lo), "v"(hi));
  return r;
}

// ---------- cast weights to bf16 (3 blocks) ----------
__global__ __launch_bounds__(256) void k_castw(const float* __restrict__ Wp, const float* __restrict__ W1,
                       const float* __restrict__ W2, u16* __restrict__ Wpb, u16* __restrict__ W1b, u16* __restrict__ W2b){
  int b = blockIdx.x, t = threadIdx.x;
  if (b == 0){ for (int i = t; i < FIN*HD; i += 256) Wpb[i] = f2b(Wp[i]); }
  else if (b == 1){ for (int i = t; i < HD*256; i += 256) W1b[i] = f2b(W1[i]); }
  else { for (int i = t; i < 256*HD; i += 256) W2b[i] = f2b(W2[i]); }
}

// ---------- MFMA GEMM: C[M,NOUT] = A[M,K] @ B[K,NOUT], bf16 (A may be f32, converted in staging) ----------
// 256 thr = 4 waves; wave w owns cols [w*CPW, w*CPW+CPW). 2 chunks of 64 rows per block.
// A/B frag: idx=lane&15, k=(lane>>4)*8+j.  C/D: col=lane&15, row=(lane>>4)*4+reg.
template<int K, int NOUT, int CPW, bool RELU_BIAS, bool DOTS, bool AF32>
__global__ __launch_bounds__(256) void k_gemm(const void* __restrict__ Av, const u16* __restrict__ B,
            const float* __restrict__ bias, const float* __restrict__ att_s, const float* __restrict__ att_d,
            u16* __restrict__ C, float* __restrict__ a_s, float* __restrict__ a_d){
  const u16* A = (const u16*)Av;
  const float* Af = (const float*)Av;
  constexpr int KT = K/32;
  constexpr int NT = CPW/16;
  constexpr int LDK = K + 8;          // +16B pad -> bank stride 4
  __shared__ u16 As[64*LDK];
  int t = threadIdx.x, w = t >> 6, l = t & 63;
  int c0 = w*CPW;
  int l16 = l & 15, kg = l >> 4;

  // B fragments (registers, loaded once)
  short8 bf[KT*NT];
#pragma unroll
  for (int kt = 0; kt < KT; ++kt)
#pragma unroll
    for (int nt = 0; nt < NT; ++nt){
      int kbase = kt*32 + kg*8;
      int col = c0 + nt*16 + l16;
      short8 v;
#pragma unroll
      for (int j = 0; j < 8; ++j) v[j] = (short)B[(size_t)(kbase + j)*NOUT + col];
      bf[kt*NT + nt] = v;
    }
  float bv = 0.f;
  if (RELU_BIAS) bv = bias[c0 + l16];
  float asv[NT], adv[NT];
  if (DOTS){
#pragma unroll
    for (int nt = 0; nt < NT; ++nt){
      asv[nt] = att_s[c0 + nt*16 + l16];
      adv[nt] = att_d[c0 + nt*16 + l16];
    }
  }

  for (int ch = 0; ch < 2; ++ch){
    int nb = (blockIdx.x*2 + ch)*64;
    if (nb >= NN) break;
    __syncthreads();
    // stage A chunk (64 rows) into padded LDS
    constexpr int UPR = K/8;   // 8-channel (16B bf16) units per row
    for (int u = t; u < 64*UPR; u += 256){
      int r = u / UPR, c = u % UPR;
      int n = nb + r;
      uint4 v = make_uint4(0u,0u,0u,0u);
      if (AF32){
        if (n < NN){
          float4 f0 = *(const float4*)&Af[(size_t)n*K + c*8];
          float4 f1 = *(const float4*)&Af[(size_t)n*K + c*8 + 4];
          v = make_uint4(pkbf16(f0.x,f0.y), pkbf16(f0.z,f0.w), pkbf16(f1.x,f1.y), pkbf16(f1.z,f1.w));
        }
      } else {
        if (n < NN) v = *(const uint4*)&A[(size_t)n*K + c*8];
      }
      *(uint4*)&As[r*LDK + c*8] = v;
    }
    __syncthreads();
#pragma unroll
    for (int rt = 0; rt < 4; ++rt){
      short8 af[KT];
#pragma unroll
      for (int kt = 0; kt < KT; ++kt)
        af[kt] = *(const short8*)&As[(rt*16 + l16)*LDK + kt*32 + kg*8];
      f32x4 acc[NT];
#pragma unroll
      for (int nt = 0; nt < NT; ++nt){
        acc[nt] = (f32x4){0.f,0.f,0.f,0.f};
#pragma unroll
        for (int kt = 0; kt < KT; ++kt)
          acc[nt] = __builtin_amdgcn_mfma_f32_16x16x32_bf16(af[kt], bf[kt*NT + nt], acc[nt], 0, 0, 0);
      }
      int rbase = nb + rt*16 + kg*4;
      // store C
#pragma unroll
      for (int nt = 0; nt < NT; ++nt)
#pragma unroll
        for (int r4 = 0; r4 < 4; ++r4){
          int n = rbase + r4;
          if (n < NN){
            float v = acc[nt][r4];
            if (RELU_BIAS) v = fmaxf(v + bv, 0.f);
            C[(size_t)n*NOUT + c0 + nt*16 + l16] = f2b(v);
          }
        }
      if (DOTS){
        // head == wave (CPW=64): per-row dot over this wave's 64 cols, f32 acc
#pragma unroll
        for (int r4 = 0; r4 < 4; ++r4){
          float ps = 0.f, pd = 0.f;
#pragma unroll
          for (int nt = 0; nt < NT; ++nt){
            ps = fmaf(acc[nt][r4], asv[nt], ps);
            pd = fmaf(acc[nt][r4], adv[nt], pd);
          }
#pragma unroll
          for (int o = 1; o < 16; o <<= 1){
            ps += __shfl_xor(ps, o, 64);
            pd += __shfl_xor(pd, o, 64);
          }
          int n = rbase + r4;
          if (l16 == 0 && n < NN){ a_s[n*NH + w] = ps; a_d[n*NH + w] = pd; }
        }
      }
    }
  }
}

// ---------- CSR build ----------

__global__ void k_hist(const int* __restrict__ ei, int* __restrict__ cnt){
  int e = blockIdx.x*256 + threadIdx.x;
  if (e < ET) atomicAdd(&cnt[edst(ei, e)], 1);
}

__global__ void k_bsum(const int* __restrict__ cnt, int* __restrict__ bsums){
  int b = blockIdx.x, t = threadIdx.x;
  int i = b*256 + t;
  int v = (i < NN) ? cnt[i] : 0;
  float s = wsum((float)v);
  __shared__ float ws4[4];
  if ((t & 63) == 0) ws4[t >> 6] = s;
  __syncthreads();
  if (t == 0) bsums[b] = (int)(ws4[0] + ws4[1] + ws4[2] + ws4[3] + 0.5f);
}

__global__ void k_boff(const int* __restrict__ bsums, int* __restrict__ boffs, int nb){
  __shared__ int s[256];
  int t = threadIdx.x;
  int v = (t < nb) ? bsums[t] : 0;
  s[t] = v; __syncthreads();
  for (int d = 1; d < 256; d <<= 1){
    int xv = (t >= d) ? s[t-d] : 0;
    __syncthreads();
    s[t] += xv;
    __syncthreads();
  }
  if (t < nb) boffs[t] = s[t] - v;
}

__global__ void k_off(const int* __restrict__ cnt, const int* __restrict__ boffs,
                      int* __restrict__ off, int* __restrict__ pos){
  int b = blockIdx.x, t = threadIdx.x;
  int i = b*256 + t;
  __shared__ int s[256];
  int v = (i < NN) ? cnt[i] : 0;
  s[t] = v; __syncthreads();
  for (int d = 1; d < 256; d <<= 1){
    int xv = (t >= d) ? s[t-d] : 0;
    __syncthreads();
    s[t] += xv;
    __syncthreads();
  }
  int excl = s[t] - v;
  if (i < NN){ int o = boffs[b] + excl; off[i] = o; pos[i] = o; }
  if (i == NN - 1) off[NN] = boffs[b] + s[t];
}

__global__ void k_scatter(const int* __restrict__ ei, int* __restrict__ pos, int* __restrict__ csrc){
  int e = blockIdx.x*256 + threadIdx.x;
  if (e < ET){
    int d = edst(ei, e);
    int idx = atomicAdd(&pos[d], 1);
    csrc[idx] = esrc(ei, e);
  }
}

// ---------- GAT layer-1 aggregation: wave = node, full 512B row per load ----------
// lane l: channels [4l, 4l+4), head h = l>>4 (constant per 16-lane group)

__global__ __launch_bounds__(256) void k_gat1(const u16* __restrict__ h1b, const float* __restrict__ a_s,
                       const float* __restrict__ a_d, const int* __restrict__ off,
                       const int* __restrict__ csrc, const float* __restrict__ b1,
                       u16* __restrict__ h1outb){
  int wv = threadIdx.x >> 6, l = threadIdx.x & 63;
  int n = blockIdx.x*4 + wv;
  if (n >= NN) return;
  int e0 = off[n], e1 = off[n+1], deg = e1 - e0;
  int j16 = l & 15, h = l >> 4;
  float adst = a_d[n*NH + h];
  float acc0 = 0.f, acc1 = 0.f, acc2 = 0.f, acc3 = 0.f;

  if (deg <= 64){
    int sreg[4]; float wreg[4];
#pragma unroll
    for (int c = 0; c < 4; ++c){
      int idx = c*16 + j16;
      int s = (idx < deg) ? csrc[e0 + idx] : 0;
      sreg[c] = s;
      wreg[c] = (idx < deg) ? lrelu(a_s[s*NH + h] + adst) : -3.0e38f;
    }
    float m = fmaxf(fmaxf(wreg[0], wreg[1]), fmaxf(wreg[2], wreg[3]));
#pragma unroll
    for (int o2 = 1; o2 < 16; o2 <<= 1) m = fmaxf(m, __shfl_xor(m, o2, 64));
    float se = 0.f;
#pragma unroll
    for (int c = 0; c < 4; ++c){
      int idx = c*16 + j16;
      float wc = (idx < deg) ? __expf(wreg[c] - m) : 0.f;
      wreg[c] = wc; se += wc;
    }
#pragma unroll
    for (int o2 = 1; o2 < 16; o2 <<= 1) se += __shfl_xor(se, o2, 64);
    float inv = 1.f / (se + 1e-16f);
#pragma unroll
    for (int c = 0; c < 4; ++c) wreg[c] *= inv;
    int srcl = l & 48;
#pragma unroll
    for (int c = 0; c < 4; ++c){
      int cbase = c*16;
      if (cbase < deg){
        int cnt = deg - cbase; if (cnt > 16) cnt = 16;
        int j2 = 0;
        for (; j2 + 4 <= cnt; j2 += 4){
          int s0 = __shfl(sreg[c], j2,   64);
          int s1 = __shfl(sreg[c], j2+1, 64);
          int s2 = __shfl(sreg[c], j2+2, 64);
          int s3 = __shfl(sreg[c], j2+3, 64);
          float w0 = __shfl(wreg[c], srcl | j2,     64);
          float w1 = __shfl(wreg[c], srcl | (j2+1), 64);
          float w2 = __shfl(wreg[c], srcl | (j2+2), 64);
          float w3 = __shfl(wreg[c], srcl | (j2+3), 64);
          ushort4 v0 = *(const ushort4*)(h1b + (size_t)s0*256 + 4*l);
          ushort4 v1 = *(const ushort4*)(h1b + (size_t)s1*256 + 4*l);
          ushort4 v2 = *(const ushort4*)(h1b + (size_t)s2*256 + 4*l);
          ushort4 v3 = *(const ushort4*)(h1b + (size_t)s3*256 + 4*l);
          acc0 = fmaf(b2f(v0.x), w0, acc0); acc1 = fmaf(b2f(v0.y), w0, acc1);
          acc2 = fmaf(b2f(v0.z), w0, acc2); acc3 = fmaf(b2f(v0.w), w0, acc3);
          acc0 = fmaf(b2f(v1.x), w1, acc0); acc1 = fmaf(b2f(v1.y), w1, acc1);
          acc2 = fmaf(b2f(v1.z), w1, acc2); acc3 = fmaf(b2f(v1.w), w1, acc3);
          acc0 = fmaf(b2f(v2.x), w2, acc0); acc1 = fmaf(b2f(v2.y), w2, acc1);
          acc2 = fmaf(b2f(v2.z), w2, acc2); acc3 = fmaf(b2f(v2.w), w2, acc3);
          acc0 = fmaf(b2f(v3.x), w3, acc0); acc1 = fmaf(b2f(v3.y), w3, acc1);
          acc2 = fmaf(b2f(v3.z), w3, acc2); acc3 = fmaf(b2f(v3.w), w3, acc3);
        }
        for (; j2 < cnt; ++j2){
          int s = __shfl(sreg[c], j2, 64);
          float wq = __shfl(wreg[c], srcl | j2, 64);
          ushort4 v = *(const ushort4*)(h1b + (size_t)s*256 + 4*l);
          acc0 = fmaf(b2f(v.x), wq, acc0); acc1 = fmaf(b2f(v.y), wq, acc1);
          acc2 = fmaf(b2f(v.z), wq, acc2); acc3 = fmaf(b2f(v.w), wq, acc3);
        }
      }
    }
  } else {
    // rare path: any degree
    float m = -3.0e38f;
    for (int i = e0 + j16; i < e1; i += 16){
      int s = csrc[i];
      m = fmaxf(m, lrelu(a_s[s*NH + h] + adst));
    }
#pragma unroll
    for (int o2 = 1; o2 < 16; o2 <<= 1) m = fmaxf(m, __shfl_xor(m, o2, 64));
    float se = 0.f;
    for (int i = e0 + j16; i < e1; i += 16){
      int s = csrc[i];
      se += __expf(lrelu(a_s[s*NH + h] + adst) - m);
    }
#pragma unroll
    for (int o2 = 1; o2 < 16; o2 <<= 1) se += __shfl_xor(se, o2, 64);
    float inv = 1.f / (se + 1e-16f);
    for (int i = e0; i < e1; ++i){
      int s = csrc[i];
      float wq = __expf(lrelu(a_s[s*NH + h] + adst) - m) * inv;
      ushort4 v = *(const ushort4*)(h1b + (size_t)s*256 + 4*l);
      acc0 = fmaf(b2f(v.x), wq, acc0); acc1 = fmaf(b2f(v.y), wq, acc1);
      acc2 = fmaf(b2f(v.z), wq, acc2); acc3 = fmaf(b2f(v.w), wq, acc3);
    }
  }
  float4 bv = *(const float4*)&b1[4*l];
  u32 lo = pkbf16(lrelu(acc0 + bv.x), lrelu(acc1 + bv.y));
  u32 hi = pkbf16(lrelu(acc2 + bv.z), lrelu(acc3 + bv.w));
  *(uint2*)&h1outb[(size_t)n*256 + 4*l] = make_uint2(lo, hi);
}

// layer-2 attention dots from h2b
__global__ __launch_bounds__(256) void k_dots2(const u16* __restrict__ h2b, const float* __restrict__ as2,
                        const float* __restrict__ ad2, float* __restrict__ a_s, float* __restrict__ a_d){
  int w = threadIdx.x >> 6, l = threadIdx.x & 63;
  int n = blockIdx.x*4 + w;
  if (n >= NN) return;
  float v = b2f(h2b[(size_t)n*HD + l]);
  float s = wsum(v * as2[l]);
  float d = wsum(v * ad2[l]);
  if (l == 0){ a_s[n] = s; a_d[n] = d; }
}

// ---------- GAT layer-2 aggregation: wave = node; 16 lanes/edge, 4 edges per iter ----------
__global__ __launch_bounds__(256) void k_gat2(const u16* __restrict__ h2b, const float* __restrict__ a_s,
                       const float* __restrict__ a_d, const int* __restrict__ off,
                       const int* __restrict__ csrc, const float* __restrict__ b2,
                       float* __restrict__ h2out){
  int wv = threadIdx.x >> 6, l = threadIdx.x & 63;
  int n = blockIdx.x*4 + wv;      // wave == node
  if (n >= NN) return;
  int e0 = off[n], e1 = off[n+1], deg = e1 - e0;
  int j16 = l & 15, g = l >> 4;
  float adst = a_d[n];
  if (deg <= 64){
    int sA = 0; float alA = -3.0e38f;
    if (l < deg){
      sA = csrc[e0 + l];
      alA = lrelu(a_s[sA] + adst);
    }
    float m = wmax(alA);
    float wA = (l < deg) ? __expf(alA - m) : 0.f;
    float se = wsum(wA);
    wA *= 1.f / (se + 1e-16f);
    float acc0 = 0.f, acc1 = 0.f, acc2 = 0.f, acc3 = 0.f;
    for (int i4 = 0; i4 < deg; i4 += 4){
      int idx = i4 + g;
      int s = __shfl(sA, idx, 64);
      float wq = __shfl(wA, idx, 64);
      if (idx < deg){
        ushort4 v = *(const ushort4*)(h2b + (size_t)s*HD + 4*j16);
        acc0 = fmaf(b2f(v.x), wq, acc0); acc1 = fmaf(b2f(v.y), wq, acc1);
        acc2 = fmaf(b2f(v.z), wq, acc2); acc3 = fmaf(b2f(v.w), wq, acc3);
      }
    }
    // cross-group reduce (4 groups)
#pragma unroll
    for (int o2 = 16; o2 < 64; o2 <<= 1){
      acc0 += __shfl_xor(acc0, o2, 64);
      acc1 += __shfl_xor(acc1, o2, 64);
      acc2 += __shfl_xor(acc2, o2, 64);
      acc3 += __shfl_xor(acc3, o2, 64);
    }
    if (l < 16){
      float4 bb = *(const float4*)&b2[4*l];
      float4 o;
      o.x = lrelu(acc0 + bb.x); o.y = lrelu(acc1 + bb.y);
      o.z = lrelu(acc2 + bb.z); o.w = lrelu(acc3 + bb.w);
      *(float4*)&h2out[(size_t)n*HD + 4*l] = o;
    }
  } else {
    // rare path: any degree; lane = channel
    float m = -3.0e38f;
    for (int i = e0 + l; i < e1; i += 64){
      int s = csrc[i];
      m = fmaxf(m, lrelu(a_s[s] + adst));
    }
    m = wmax(m);
    float se = 0.f;
    for (int i = e0 + l; i < e1; i += 64){
      int s = csrc[i];
      se += __expf(lrelu(a_s[s] + adst) - m);
    }
    se = wsum(se);
    float inv = 1.f / (se + 1e-16f);
    float acc = 0.f;
    for (int i = e0; i < e1; ++i){
      int s = csrc[i];
      acc += b2f(h2b[(size_t)s*HD + l]) * __expf(lrelu(a_s[s] + adst) - m);
    }
    h2out[(size_t)n*HD + l] = lrelu(acc*inv + b2[l]);
  }
}

// ---------- pooling ----------

__global__ void k_pool(const float* __restrict__ h2out, const int* __restrict__ batch,
                       float* __restrict__ gsum, unsigned* __restrict__ gmaxk, int* __restrict__ gcnt){
  __shared__ float ssum[NGR*HD];
  __shared__ unsigned smax[NGR*HD];
  __shared__ int scnt[NGR];
  int t = threadIdx.x;   // 256
  for (int i = t; i < NGR*HD; i += 256){ ssum[i] = 0.f; smax[i] = 0u; }
  if (t < NGR) scnt[t] = 0;
  __syncthreads();
  int wv = t >> 6, lane = t & 63;
  for (int n = blockIdx.x*4 + wv; n < NN; n += gridDim.x*4){
    int g = batch[n];
    float v = h2out[(size_t)n*HD + lane];
    atomicAdd(&ssum[g*HD + lane], v);
    atomicMax(&smax[g*HD + lane], f2key(v));
    if (lane == 0) atomicAdd(&scnt[g], 1);
  }
  __syncthreads();
  for (int i = t; i < NGR*HD; i += 256){
    atomicAdd(&gsum[i], ssum[i]);
    atomicMax(&gmaxk[i], smax[i]);
  }
  if (t < NGR) atomicAdd(&gcnt[t], scnt[t]);
}

// ---------- final MLP + log_softmax ----------

__global__ void k_final(const float* __restrict__ gsum, const unsigned* __restrict__ gmaxk,
                        const int* __restrict__ gcnt,
                        const float* __restrict__ Wf1, const float* __restrict__ bf1,
                        const float* __restrict__ Wf2, const float* __restrict__ bf2,
                        float* __restrict__ out){
  int g = blockIdx.x, t = threadIdx.x;  // 64 threads
  __shared__ float gv[HD];
  __shared__ float f1[32];
  __shared__ float lg[NCL];
  int c = gcnt[g];
  float dn = fmaxf((float)c, 1.f);
  float mean = gsum[g*HD + t] / dn;
  float mx = (c > 0) ? key2f(gmaxk[g*HD + t]) : 0.f;
  gv[t] = mean + mx;
  __syncthreads();
  if (t < 32){
    float a = bf1[t];
#pragma unroll
    for (int k = 0; k < HD; ++k) a += gv[k] * Wf1[k*32 + t];
    f1[t] = a > 0.f ? a : 0.f;
  }
  __syncthreads();
  if (t < NCL){
    float a = bf2[t];
#pragma unroll
    for (int k = 0; k < 32; ++k) a += f1[k] * Wf2[k*NCL + t];
    lg[t] = a;
  }
  __syncthreads();
  if (t < NCL){
    float m = lg[0];
#pragma unroll
    for (int i = 1; i < NCL; ++i) m = fmaxf(m, lg[i]);
    float s = 0.f;
#pragma unroll
    for (int i = 0; i < NCL; ++i) s += expf(lg[i] - m);
    out[g*NCL + t] = lg[t] - m - logf(s);
  }
}

extern "C" void kernel_launch(void* const* d_in, const int* in_sizes, int n_in,
                              void* d_out, int out_size, void* d_ws, size_t ws_size,
                              hipStream_t stream) {
  const float* x   = (const float*)d_in[0];
  const int*   ei  = (const int*)d_in[1];
  const int*   bat = (const int*)d_in[2];
  const float* Wp  = (const float*)d_in[3];
  const float* bp  = (const float*)d_in[4];
  const float* W1  = (const float*)d_in[5];
  const float* as1 = (const float*)d_in[6];
  const float* ad1 = (const float*)d_in[7];
  const float* b1  = (const float*)d_in[8];
  const float* W2  = (const float*)d_in[9];
  const float* as2 = (const float*)d_in[10];
  const float* ad2 = (const float*)d_in[11];
  const float* b2  = (const float*)d_in[12];
  const float* Wf1 = (const float*)d_in[13];
  const float* bf1 = (const float*)d_in[14];
  const float* Wf2 = (const float*)d_in[15];
  const float* bf2 = (const float*)d_in[16];
  float* out = (float*)d_out;

  char* base = (char*)d_ws;
  size_t o = 0;
  auto alloc = [&](size_t elems) -> char* {   // elems are 4-byte units
    char* p = base + o*4;
    o += (elems + 63) & ~(size_t)63;
    return p;
  };
  u16*   Wpb    = (u16*)alloc(4096);         // [128,64]
  u16*   W1b    = (u16*)alloc(8192);         // [64,256]
  u16*   W2b    = (u16*)alloc(8192);         // [256,64]
  u16*   h0b    = (u16*)alloc(1600000);      // [NN,64] bf16
  u16*   h1b    = (u16*)alloc(6400000);      // [NN,256] bf16
  u16*   h1outb = (u16*)alloc(6400000);      // [NN,256] bf16
  u16*   h2b    = (u16*)alloc(800000);       // [NN,64] bf16
  float* h2out  = (float*)alloc(3200000);    // [NN,64] f32
  float* a_s1   = (float*)alloc(200000);
  float* a_d1   = (float*)alloc(200000);
  float* a_s2   = (float*)alloc(50000);
  float* a_d2   = (float*)alloc(50000);
  int*   cnt    = (int*)alloc(50000);
  int*   off    = (int*)alloc(50001);
  int*   pos    = (int*)alloc(50000);
  int*   bsums  = (int*)alloc(256);
  int*   boffs  = (int*)alloc(256);
  int*   csrc   = (int*)alloc(850000);
  float* gsum   = (float*)alloc(NGR*HD);
  unsigned* gmaxk = (unsigned*)alloc(NGR*HD);
  int*   gcnt   = (int*)alloc(NGR);

  const int NB = (NN + 255) / 256;
  const int EB = (ET + 255) / 256;
  const int GB = (NN + 127) / 128;    // gemm blocks (2x64 rows each)
  const int WB = (NN + 3) / 4;        // wave-per-node blocks

  // CSR build
  hipMemsetAsync(cnt, 0, NN*sizeof(int), stream);
  k_hist<<<EB, 256, 0, stream>>>(ei, cnt);
  k_bsum<<<NB, 256, 0, stream>>>(cnt, bsums);
  k_boff<<<1, 256, 0, stream>>>(bsums, boffs, NB);
  k_off<<<NB, 256, 0, stream>>>(cnt, boffs, off, pos);
  k_scatter<<<EB, 256, 0, stream>>>(ei, pos, csrc);

  // weights to bf16
  k_castw<<<3, 256, 0, stream>>>(Wp, W1, W2, Wpb, W1b, W2b);

  // dense front-end (MFMA); x cast fused into proj staging
  k_gemm<128, 64, 16, true, false, true><<<GB, 256, 0, stream>>>(x, Wpb, bp, nullptr, nullptr, h0b, nullptr, nullptr);
  k_gemm<64, 256, 64, false, true, false><<<GB, 256, 0, stream>>>(h0b, W1b, nullptr, as1, ad1, h1b, a_s1, a_d1);

  // GAT layer 1
  k_gat1<<<WB, 256, 0, stream>>>(h1b, a_s1, a_d1, off, csrc, b1, h1outb);

  // GAT layer 2
  k_gemm<256, 64, 16, false, false, false><<<GB, 256, 0, stream>>>(h1outb, W2b, nullptr, nullptr, nullptr, h2b, nullptr, nullptr);
  k_dots2<<<WB, 256, 0, stream>>>(h2b, as2, ad2, a_s2, a_d2);
  k_gat2<<<WB, 256, 0, stream>>>(h2b, a_s2, a_d2, off, csrc, b2, h2out);

  // pooling
  hipMemsetAsync(gsum, 0, (NGR*HD*2 + 64)*sizeof(int), stream);
  k_pool<<<256, 256, 0, stream>>>(h2out, bat, gsum, gmaxk, gcnt);

  // head MLP + log_softmax
  k_final<<<NGR, 64, 0, stream>>>(gsum, gmaxk, gcnt, Wf1, bf1, Wf2, bf2, out);
}

// Round 7
// 275.168 us; speedup vs baseline: 2.5574x; 1.0955x over previous
//
#include <hip/hip_runtime.h>
#include <math.h>

#define NN 50000
#define EE 800000
#define ET 850000    // EE + NN self loops
#define FIN 128
#define HD 64
#define NH 4
#define NGR 64
#define NCL 10
#define NEG 0.2f

typedef unsigned short u16;
typedef unsigned int u32;
typedef __attribute__((ext_vector_type(8))) short short8;
typedef __attribute__((ext_vector_type(4))) float f32x4;

__device__ __forceinline__ float lrelu(float x){ return x > 0.f ? x : NEG * x; }

__device__ __forceinline__ float wsum(float v){
#pragma unroll
  for (int o = 32; o > 0; o >>= 1) v += __shfl_xor(v, o, 64);
  return v;
}
__device__ __forceinline__ float wmax(float v){
#pragma unroll
  for (int o = 32; o > 0; o >>= 1) v = fmaxf(v, __shfl_xor(v, o, 64));
  return v;
}
__device__ __forceinline__ int esrc(const int* ei, int e){ return e < EE ? ei[e] : e - EE; }
__device__ __forceinline__ int edst(const int* ei, int e){ return e < EE ? ei[EE + e] : e - EE; }

__device__ __forceinline__ unsigned f2key(float f){
  unsigned u = __float_as_uint(f);
  return (u & 0x80000000u) ? ~u : (u | 0x80000000u);
}
__device__ __forceinline__ float key2f(unsigned k){
  return (k & 0x80000000u) ? __uint_as_float(k & 0x7fffffffu) : __uint_as_float(~k);
}

// bf16 pack (RNE) / unpack
__device__ __forceinline__ u16 f2b(float f){
  u32 u = __float_as_uint(f);
  u32 r = (u + 0x7FFFu + ((u >> 16) & 1u)) >> 16;
  return (u16)r;
}
__device__ __forceinline__ float b2f(u16 b){ return __uint_as_float(((u32)b) << 16); }
__device__ __forceinline__ u32 pkbf16(float lo, float hi){
  u32 r;
  asm("v_cvt_pk_bf16_f32 %0, %1, %2" : "=v"(r) : "v"(lo), "v"(hi));
  return r;
}
// uniform readlane (idx may be runtime-uniform)
__device__ __forceinline__ int rl(int v, int idx){ return __builtin_amdgcn_readlane(v, idx); }
__device__ __forceinline__ float rlf(float v, int idx){
  return __uint_as_float((u32)__builtin_amdgcn_readlane((int)__float_as_uint(v), idx));
}

// ---------- MFMA GEMM body: C[M,NOUT] = A[M,K] @ B[K,NOUT]; B is f32 (converted here) ----------
// 256 thr = 4 waves; wave w owns cols [w*CPW, w*CPW+CPW). 2 chunks of 64 rows per block.
// A/B frag: idx=lane&15, k=(lane>>4)*8+j.  C/D: col=lane&15, row=(lane>>4)*4+reg.
template<int K, int NOUT, int CPW, bool RELU_BIAS, bool DOTS1, bool DOTS2, bool AF32>
__device__ __forceinline__ void gemm_body(int bid, u16* As, float* sred,
            const void* __restrict__ Av, const float* __restrict__ Bf,
            const float* __restrict__ bias, const float* __restrict__ att_s, const float* __restrict__ att_d,
            u16* __restrict__ C, float* __restrict__ a_s, float* __restrict__ a_d){
  const u16* A = (const u16*)Av;
  const float* Af = (const float*)Av;
  constexpr int KT = K/32;
  constexpr int NT = CPW/16;
  constexpr int LDK = K + 8;          // +16B pad -> bank stride 4
  int t = threadIdx.x, w = t >> 6, l = t & 63;
  int c0 = w*CPW;
  int l16 = l & 15, kg = l >> 4;

  // B fragments (registers, converted f32->bf16 once per block)
  short8 bf[KT*NT];
#pragma unroll
  for (int kt = 0; kt < KT; ++kt)
#pragma unroll
    for (int nt = 0; nt < NT; ++nt){
      int kbase = kt*32 + kg*8;
      int col = c0 + nt*16 + l16;
      short8 v;
#pragma unroll
      for (int j = 0; j < 8; ++j) v[j] = (short)f2b(Bf[(size_t)(kbase + j)*NOUT + col]);
      bf[kt*NT + nt] = v;
    }
  float bv = 0.f;
  if (RELU_BIAS) bv = bias[c0 + l16];
  float asv[NT], adv[NT];
  if (DOTS1 || DOTS2){
#pragma unroll
    for (int nt = 0; nt < NT; ++nt){
      asv[nt] = att_s[c0 + nt*16 + l16];
      adv[nt] = att_d[c0 + nt*16 + l16];
    }
  }

  for (int ch = 0; ch < 2; ++ch){
    int nb = (bid*2 + ch)*64;
    if (nb >= NN) break;
    __syncthreads();
    // stage A chunk (64 rows) into padded LDS
    constexpr int UPR = K/8;   // 8-channel (16B bf16) units per row
    for (int u = t; u < 64*UPR; u += 256){
      int r = u / UPR, c = u % UPR;
      int n = nb + r;
      uint4 v = make_uint4(0u,0u,0u,0u);
      if (AF32){
        if (n < NN){
          float4 f0 = *(const float4*)&Af[(size_t)n*K + c*8];
          float4 f1 = *(const float4*)&Af[(size_t)n*K + c*8 + 4];
          v = make_uint4(pkbf16(f0.x,f0.y), pkbf16(f0.z,f0.w), pkbf16(f1.x,f1.y), pkbf16(f1.z,f1.w));
        }
      } else {
        if (n < NN) v = *(const uint4*)&A[(size_t)n*K + c*8];
      }
      *(uint4*)&As[r*LDK + c*8] = v;
    }
    __syncthreads();
#pragma unroll
    for (int rt = 0; rt < 4; ++rt){
      short8 af[KT];
#pragma unroll
      for (int kt = 0; kt < KT; ++kt)
        af[kt] = *(const short8*)&As[(rt*16 + l16)*LDK + kt*32 + kg*8];
      f32x4 acc[NT];
#pragma unroll
      for (int nt = 0; nt < NT; ++nt){
        acc[nt] = (f32x4){0.f,0.f,0.f,0.f};
#pragma unroll
        for (int kt = 0; kt < KT; ++kt)
          acc[nt] = __builtin_amdgcn_mfma_f32_16x16x32_bf16(af[kt], bf[kt*NT + nt], acc[nt], 0, 0, 0);
      }
      int rbase = nb + rt*16 + kg*4;
      // store C
#pragma unroll
      for (int nt = 0; nt < NT; ++nt)
#pragma unroll
        for (int r4 = 0; r4 < 4; ++r4){
          int n = rbase + r4;
          if (n < NN){
            float v = acc[nt][r4];
            if (RELU_BIAS) v = fmaxf(v + bv, 0.f);
            C[(size_t)n*NOUT + c0 + nt*16 + l16] = f2b(v);
          }
        }
      if (DOTS1){
        // head == wave (CPW=64): per-row dot over this wave's 64 cols, f32 acc
#pragma unroll
        for (int r4 = 0; r4 < 4; ++r4){
          float ps = 0.f, pd = 0.f;
#pragma unroll
          for (int nt = 0; nt < NT; ++nt){
            ps = fmaf(acc[nt][r4], asv[nt], ps);
            pd = fmaf(acc[nt][r4], adv[nt], pd);
          }
#pragma unroll
          for (int o = 1; o < 16; o <<= 1){
            ps += __shfl_xor(ps, o, 64);
            pd += __shfl_xor(pd, o, 64);
          }
          int n = rbase + r4;
          if (l16 == 0 && n < NN){ a_s[n*NH + w] = ps; a_d[n*NH + w] = pd; }
        }
      }
      if (DOTS2){
        // per-wave partial dot over its 16 cols (NT==1); full reduce via LDS after rt loop
#pragma unroll
        for (int r4 = 0; r4 < 4; ++r4){
          float ps = acc[0][r4]*asv[0];
          float pd = acc[0][r4]*adv[0];
#pragma unroll
          for (int o = 1; o < 16; o <<= 1){
            ps += __shfl_xor(ps, o, 64);
            pd += __shfl_xor(pd, o, 64);
          }
          if (l16 == 0){
            int row = rt*16 + kg*4 + r4;
            sred[(w*64 + row)*2]     = ps;
            sred[(w*64 + row)*2 + 1] = pd;
          }
        }
      }
    }
    if (DOTS2){
      __syncthreads();
      if (t < 64){
        int n = nb + t;
        if (n < NN){
          float s = sred[t*2] + sred[(64+t)*2] + sred[(128+t)*2] + sred[(192+t)*2];
          float d = sred[t*2+1] + sred[(64+t)*2+1] + sred[(128+t)*2+1] + sred[(192+t)*2+1];
          a_s[n] = s; a_d[n] = d;
        }
      }
    }
  }
}

// ---------- fused: hist (CSR histogram) || proj GEMM ----------
__global__ __launch_bounds__(256) void k_hist_proj(const int* __restrict__ ei, int* __restrict__ cnt,
            const float* __restrict__ x, const float* __restrict__ Wp, const float* __restrict__ bp,
            u16* __restrict__ h0b, int gb){
  __shared__ u16 As[64*(FIN+8)];
  int b = blockIdx.x;
  if (b < gb){
    gemm_body<128, 64, 16, true, false, false, true>(b, As, nullptr, x, Wp, bp, nullptr, nullptr, h0b, nullptr, nullptr);
  } else {
    int e = (b - gb)*256 + threadIdx.x;
    if (e < ET) atomicAdd(&cnt[edst(ei, e)], 1);
  }
}

// ---------- CSR scan kernels ----------
__global__ void k_bsum(const int* __restrict__ cnt, int* __restrict__ bsums){
  int b = blockIdx.x, t = threadIdx.x;
  int i = b*256 + t;
  int v = (i < NN) ? cnt[i] : 0;
  float s = wsum((float)v);
  __shared__ float ws4[4];
  if ((t & 63) == 0) ws4[t >> 6] = s;
  __syncthreads();
  if (t == 0) bsums[b] = (int)(ws4[0] + ws4[1] + ws4[2] + ws4[3] + 0.5f);
}

__global__ void k_boff(const int* __restrict__ bsums, int* __restrict__ boffs, int nb){
  __shared__ int s[256];
  int t = threadIdx.x;
  int v = (t < nb) ? bsums[t] : 0;
  s[t] = v; __syncthreads();
  for (int d = 1; d < 256; d <<= 1){
    int xv = (t >= d) ? s[t-d] : 0;
    __syncthreads();
    s[t] += xv;
    __syncthreads();
  }
  if (t < nb) boffs[t] = s[t] - v;
}

__global__ void k_off(const int* __restrict__ cnt, const int* __restrict__ boffs,
                      int* __restrict__ off, int* __restrict__ pos){
  int b = blockIdx.x, t = threadIdx.x;
  int i = b*256 + t;
  __shared__ int s[256];
  int v = (i < NN) ? cnt[i] : 0;
  s[t] = v; __syncthreads();
  for (int d = 1; d < 256; d <<= 1){
    int xv = (t >= d) ? s[t-d] : 0;
    __syncthreads();
    s[t] += xv;
    __syncthreads();
  }
  int excl = s[t] - v;
  if (i < NN){ int o = boffs[b] + excl; off[i] = o; pos[i] = o; }
  if (i == NN - 1) off[NN] = boffs[b] + s[t];
}

// ---------- fused: scatter || feat1 GEMM (with attention dots) ----------
__global__ __launch_bounds__(256) void k_scat_feat1(const int* __restrict__ ei, int* __restrict__ pos,
            int* __restrict__ csrc, const u16* __restrict__ h0b, const float* __restrict__ W1,
            const float* __restrict__ as1, const float* __restrict__ ad1,
            u16* __restrict__ h1b, float* __restrict__ a_s, float* __restrict__ a_d, int gb){
  __shared__ u16 As[64*(HD+8)];
  int b = blockIdx.x;
  if (b < gb){
    gemm_body<64, 256, 64, false, true, false, false>(b, As, nullptr, h0b, W1, nullptr, as1, ad1, h1b, a_s, a_d);
  } else {
    int e = (b - gb)*256 + threadIdx.x;
    if (e < ET){
      int d = edst(ei, e);
      int idx = atomicAdd(&pos[d], 1);
      csrc[idx] = esrc(ei, e);
    }
  }
}

// ---------- feat2 GEMM with fused layer-2 dots ----------
__global__ __launch_bounds__(256) void k_feat2(const u16* __restrict__ h1outb, const float* __restrict__ W2,
            const float* __restrict__ as2, const float* __restrict__ ad2,
            u16* __restrict__ h2b, float* __restrict__ a_s, float* __restrict__ a_d){
  __shared__ u16 As[64*(256+8)];
  __shared__ float sred[4*64*2];
  gemm_body<256, 64, 16, false, false, true, false>(blockIdx.x, As, sred, h1outb, W2, nullptr, as2, ad2, h2b, a_s, a_d);
}

// ---------- GAT layer-1 aggregation: wave = node, 512B row/load, scalar-base gather ----------
__global__ __launch_bounds__(256) void k_gat1(const u16* __restrict__ h1b, const float* __restrict__ a_s,
                       const float* __restrict__ a_d, const int* __restrict__ off,
                       const int* __restrict__ csrc, const float* __restrict__ b1,
                       u16* __restrict__ h1outb){
  __shared__ float lw[4][4][68];   // [wave][head][64 + 4 pad]
  int wv = threadIdx.x >> 6, l = threadIdx.x & 63;
  int n = blockIdx.x*4 + wv;
  if (n >= NN) return;
  int e0 = off[n], e1 = off[n+1], deg = e1 - e0;
  int j16 = l & 15, h = l >> 4;
  float adst = a_d[n*NH + h];
  float acc0 = 0.f, acc1 = 0.f, acc2 = 0.f, acc3 = 0.f;

  if (deg <= 64){
    int sreg[4]; float wreg[4];
#pragma unroll
    for (int c = 0; c < 4; ++c){
      int idx = c*16 + j16;
      int s = (idx < deg) ? csrc[e0 + idx] : 0;
      sreg[c] = s;
      wreg[c] = (idx < deg) ? lrelu(a_s[s*NH + h] + adst) : -3.0e38f;
    }
    float m = fmaxf(fmaxf(wreg[0], wreg[1]), fmaxf(wreg[2], wreg[3]));
#pragma unroll
    for (int o2 = 1; o2 < 16; o2 <<= 1) m = fmaxf(m, __shfl_xor(m, o2, 64));
    float se = 0.f;
#pragma unroll
    for (int c = 0; c < 4; ++c){
      int idx = c*16 + j16;
      float wc = (idx < deg) ? __expf(wreg[c] - m) : 0.f;
      wreg[c] = wc; se += wc;
    }
#pragma unroll
    for (int o2 = 1; o2 < 16; o2 <<= 1) se += __shfl_xor(se, o2, 64);
    float inv = 1.f / (se + 1e-16f);
#pragma unroll
    for (int c = 0; c < 4; ++c) lw[wv][h][c*16 + j16] = wreg[c] * inv;   // same-wave LDS, no barrier

#pragma unroll
    for (int c = 0; c < 4; ++c){
      int cbase = c*16;
      if (cbase < deg){
        int cnt = deg - cbase; if (cnt > 16) cnt = 16;
        int j2 = 0;
        for (; j2 + 4 <= cnt; j2 += 4){
          float4 wq = *(const float4*)&lw[wv][h][cbase + j2];
          int s0 = rl(sreg[c], j2);
          int s1 = rl(sreg[c], j2+1);
          int s2 = rl(sreg[c], j2+2);
          int s3 = rl(sreg[c], j2+3);
          ushort4 v0 = *(const ushort4*)(h1b + (size_t)(u32)s0*256 + 4*l);
          ushort4 v1 = *(const ushort4*)(h1b + (size_t)(u32)s1*256 + 4*l);
          ushort4 v2 = *(const ushort4*)(h1b + (size_t)(u32)s2*256 + 4*l);
          ushort4 v3 = *(const ushort4*)(h1b + (size_t)(u32)s3*256 + 4*l);
          acc0 = fmaf(b2f(v0.x), wq.x, acc0); acc1 = fmaf(b2f(v0.y), wq.x, acc1);
          acc2 = fmaf(b2f(v0.z), wq.x, acc2); acc3 = fmaf(b2f(v0.w), wq.x, acc3);
          acc0 = fmaf(b2f(v1.x), wq.y, acc0); acc1 = fmaf(b2f(v1.y), wq.y, acc1);
          acc2 = fmaf(b2f(v1.z), wq.y, acc2); acc3 = fmaf(b2f(v1.w), wq.y, acc3);
          acc0 = fmaf(b2f(v2.x), wq.z, acc0); acc1 = fmaf(b2f(v2.y), wq.z, acc1);
          acc2 = fmaf(b2f(v2.z), wq.z, acc2); acc3 = fmaf(b2f(v2.w), wq.z, acc3);
          acc0 = fmaf(b2f(v3.x), wq.w, acc0); acc1 = fmaf(b2f(v3.y), wq.w, acc1);
          acc2 = fmaf(b2f(v3.z), wq.w, acc2); acc3 = fmaf(b2f(v3.w), wq.w, acc3);
        }
        for (; j2 < cnt; ++j2){
          float wqs = lw[wv][h][cbase + j2];
          int s = rl(sreg[c], j2);
          ushort4 v = *(const ushort4*)(h1b + (size_t)(u32)s*256 + 4*l);
          acc0 = fmaf(b2f(v.x), wqs, acc0); acc1 = fmaf(b2f(v.y), wqs, acc1);
          acc2 = fmaf(b2f(v.z), wqs, acc2); acc3 = fmaf(b2f(v.w), wqs, acc3);
        }
      }
    }
  } else {
    // rare path: any degree
    float m = -3.0e38f;
    for (int i = e0 + j16; i < e1; i += 16){
      int s = csrc[i];
      m = fmaxf(m, lrelu(a_s[s*NH + h] + adst));
    }
#pragma unroll
    for (int o2 = 1; o2 < 16; o2 <<= 1) m = fmaxf(m, __shfl_xor(m, o2, 64));
    float se = 0.f;
    for (int i = e0 + j16; i < e1; i += 16){
      int s = csrc[i];
      se += __expf(lrelu(a_s[s*NH + h] + adst) - m);
    }
#pragma unroll
    for (int o2 = 1; o2 < 16; o2 <<= 1) se += __shfl_xor(se, o2, 64);
    float inv = 1.f / (se + 1e-16f);
    for (int i = e0; i < e1; ++i){
      int s = csrc[i];
      float wq = __expf(lrelu(a_s[s*NH + h] + adst) - m) * inv;
      ushort4 v = *(const ushort4*)(h1b + (size_t)s*256 + 4*l);
      acc0 = fmaf(b2f(v.x), wq, acc0); acc1 = fmaf(b2f(v.y), wq, acc1);
      acc2 = fmaf(b2f(v.z), wq, acc2); acc3 = fmaf(b2f(v.w), wq, acc3);
    }
  }
  float4 bv = *(const float4*)&b1[4*l];
  u32 lo = pkbf16(lrelu(acc0 + bv.x), lrelu(acc1 + bv.y));
  u32 hi = pkbf16(lrelu(acc2 + bv.z), lrelu(acc3 + bv.w));
  *(uint2*)&h1outb[(size_t)n*256 + 4*l] = make_uint2(lo, hi);
}

// ---------- GAT layer-2 aggregation: wave = node; 1 edge/iter, 64 lanes x 2B; s,w uniform ----------
__global__ __launch_bounds__(256) void k_gat2(const u16* __restrict__ h2b, const float* __restrict__ a_s,
                       const float* __restrict__ a_d, const int* __restrict__ off,
                       const int* __restrict__ csrc, const float* __restrict__ b2v,
                       float* __restrict__ h2out){
  int wv = threadIdx.x >> 6, l = threadIdx.x & 63;
  int n = blockIdx.x*4 + wv;      // wave == node
  if (n >= NN) return;
  int e0 = off[n], e1 = off[n+1], deg = e1 - e0;
  float adst = a_d[n];
  if (deg <= 64){
    int sA = 0; float alA = -3.0e38f;
    if (l < deg){
      sA = csrc[e0 + l];
      alA = lrelu(a_s[sA] + adst);
    }
    float m = wmax(alA);
    float wA = (l < deg) ? __expf(alA - m) : 0.f;
    float se = wsum(wA);
    wA *= 1.f / (se + 1e-16f);
    float acc = 0.f;
    int idx = 0;
    for (; idx + 4 <= deg; idx += 4){
      int s0 = rl(sA, idx),   s1 = rl(sA, idx+1);
      int s2 = rl(sA, idx+2), s3 = rl(sA, idx+3);
      float w0 = rlf(wA, idx),   w1 = rlf(wA, idx+1);
      float w2 = rlf(wA, idx+2), w3 = rlf(wA, idx+3);
      float v0 = b2f(h2b[(size_t)(u32)s0*HD + l]);
      float v1 = b2f(h2b[(size_t)(u32)s1*HD + l]);
      float v2 = b2f(h2b[(size_t)(u32)s2*HD + l]);
      float v3 = b2f(h2b[(size_t)(u32)s3*HD + l]);
      acc = fmaf(v0, w0, acc); acc = fmaf(v1, w1, acc);
      acc = fmaf(v2, w2, acc); acc = fmaf(v3, w3, acc);
    }
    for (; idx < deg; ++idx){
      int s = rl(sA, idx);
      float w = rlf(wA, idx);
      acc = fmaf(b2f(h2b[(size_t)(u32)s*HD + l]), w, acc);
    }
    h2out[(size_t)n*HD + l] = lrelu(acc + b2v[l]);
  } else {
    // rare path: any degree; lane = channel
    float m = -3.0e38f;
    for (int i = e0 + l; i < e1; i += 64){
      int s = csrc[i];
      m = fmaxf(m, lrelu(a_s[s] + adst));
    }
    m = wmax(m);
    float se = 0.f;
    for (int i = e0 + l; i < e1; i += 64){
      int s = csrc[i];
      se += __expf(lrelu(a_s[s] + adst) - m);
    }
    se = wsum(se);
    float inv = 1.f / (se + 1e-16f);
    float acc = 0.f;
    for (int i = e0; i < e1; ++i){
      int s = csrc[i];
      acc += b2f(h2b[(size_t)s*HD + l]) * __expf(lrelu(a_s[s] + adst) - m);
    }
    h2out[(size_t)n*HD + l] = lrelu(acc*inv + b2v[l]);
  }
}

// ---------- pooling ----------

__global__ void k_pool(const float* __restrict__ h2out, const int* __restrict__ batch,
                       float* __restrict__ gsum, unsigned* __restrict__ gmaxk, int* __restrict__ gcnt){
  __shared__ float ssum[NGR*HD];
  __shared__ unsigned smax[NGR*HD];
  __shared__ int scnt[NGR];
  int t = threadIdx.x;   // 256
  for (int i = t; i < NGR*HD; i += 256){ ssum[i] = 0.f; smax[i] = 0u; }
  if (t < NGR) scnt[t] = 0;
  __syncthreads();
  int wv = t >> 6, lane = t & 63;
  for (int n = blockIdx.x*4 + wv; n < NN; n += gridDim.x*4){
    int g = batch[n];
    float v = h2out[(size_t)n*HD + lane];
    atomicAdd(&ssum[g*HD + lane], v);
    atomicMax(&smax[g*HD + lane], f2key(v));
    if (lane == 0) atomicAdd(&scnt[g], 1);
  }
  __syncthreads();
  for (int i = t; i < NGR*HD; i += 256){
    atomicAdd(&gsum[i], ssum[i]);
    atomicMax(&gmaxk[i], smax[i]);
  }
  if (t < NGR) atomicAdd(&gcnt[t], scnt[t]);
}

// ---------- final MLP + log_softmax ----------

__global__ void k_final(const float* __restrict__ gsum, const unsigned* __restrict__ gmaxk,
                        const int* __restrict__ gcnt,
                        const float* __restrict__ Wf1, const float* __restrict__ bf1,
                        const float* __restrict__ Wf2, const float* __restrict__ bf2,
                        float* __restrict__ out){
  int g = blockIdx.x, t = threadIdx.x;  // 64 threads
  __shared__ float gv[HD];
  __shared__ float f1[32];
  __shared__ float lg[NCL];
  int c = gcnt[g];
  float dn = fmaxf((float)c, 1.f);
  float mean = gsum[g*HD + t] / dn;
  float mx = (c > 0) ? key2f(gmaxk[g*HD + t]) : 0.f;
  gv[t] = mean + mx;
  __syncthreads();
  if (t < 32){
    float a = bf1[t];
#pragma unroll
    for (int k = 0; k < HD; ++k) a += gv[k] * Wf1[k*32 + t];
    f1[t] = a > 0.f ? a : 0.f;
  }
  __syncthreads();
  if (t < NCL){
    float a = bf2[t];
#pragma unroll
    for (int k = 0; k < 32; ++k) a += f1[k] * Wf2[k*NCL + t];
    lg[t] = a;
  }
  __syncthreads();
  if (t < NCL){
    float m = lg[0];
#pragma unroll
    for (int i = 1; i < NCL; ++i) m = fmaxf(m, lg[i]);
    float s = 0.f;
#pragma unroll
    for (int i = 0; i < NCL; ++i) s += expf(lg[i] - m);
    out[g*NCL + t] = lg[t] - m - logf(s);
  }
}

extern "C" void kernel_launch(void* const* d_in, const int* in_sizes, int n_in,
                              void* d_out, int out_size, void* d_ws, size_t ws_size,
                              hipStream_t stream) {
  const float* x   = (const float*)d_in[0];
  const int*   ei  = (const int*)d_in[1];
  const int*   bat = (const int*)d_in[2];
  const float* Wp  = (const float*)d_in[3];
  const float* bp  = (const float*)d_in[4];
  const float* W1  = (const float*)d_in[5];
  const float* as1 = (const float*)d_in[6];
  const float* ad1 = (const float*)d_in[7];
  const float* b1  = (const float*)d_in[8];
  const float* W2  = (const float*)d_in[9];
  const float* as2 = (const float*)d_in[10];
  const float* ad2 = (const float*)d_in[11];
  const float* b2  = (const float*)d_in[12];
  const float* Wf1 = (const float*)d_in[13];
  const float* bf1 = (const float*)d_in[14];
  const float* Wf2 = (const float*)d_in[15];
  const float* bf2 = (const float*)d_in[16];
  float* out = (float*)d_out;

  char* base = (char*)d_ws;
  size_t o = 0;
  auto alloc = [&](size_t elems) -> char* {   // elems are 4-byte units
    char* p = base + o*4;
    o += (elems + 63) & ~(size_t)63;
    return p;
  };
  u16*   h0b    = (u16*)alloc(1600000);      // [NN,64] bf16
  u16*   h1b    = (u16*)alloc(6400000);      // [NN,256] bf16
  u16*   h1outb = (u16*)alloc(6400000);      // [NN,256] bf16
  u16*   h2b    = (u16*)alloc(800000);       // [NN,64] bf16
  float* h2out  = (float*)alloc(3200000);    // [NN,64] f32
  float* a_s1   = (float*)alloc(200000);
  float* a_d1   = (float*)alloc(200000);
  float* a_s2   = (float*)alloc(50000);
  float* a_d2   = (float*)alloc(50000);
  int*   cnt    = (int*)alloc(50000);
  int*   off    = (int*)alloc(50001);
  int*   pos    = (int*)alloc(50000);
  int*   bsums  = (int*)alloc(256);
  int*   boffs  = (int*)alloc(256);
  int*   csrc   = (int*)alloc(850000);
  float* gsum   = (float*)alloc(NGR*HD);
  unsigned* gmaxk = (unsigned*)alloc(NGR*HD);
  int*   gcnt   = (int*)alloc(NGR);

  const int NB = (NN + 255) / 256;     // 196
  const int EB = (ET + 255) / 256;     // 3321
  const int GB = (NN + 127) / 128;     // 391 gemm blocks (2x64 rows each)
  const int WB = (NN + 3) / 4;         // wave-per-node blocks

  // zero scratch up front (both independent of everything else)
  hipMemsetAsync(cnt, 0, NN*sizeof(int), stream);
  hipMemsetAsync(gsum, 0, (NGR*HD*2 + 64)*sizeof(int), stream);

  // L1: proj GEMM || CSR histogram
  k_hist_proj<<<GB + EB, 256, 0, stream>>>(ei, cnt, x, Wp, bp, h0b, GB);
  // L2-4: CSR scan (small)
  k_bsum<<<NB, 256, 0, stream>>>(cnt, bsums);
  k_boff<<<1, 256, 0, stream>>>(bsums, boffs, NB);
  k_off<<<NB, 256, 0, stream>>>(cnt, boffs, off, pos);
  // L5: feat1 GEMM (+dots) || scatter
  k_scat_feat1<<<GB + EB, 256, 0, stream>>>(ei, pos, csrc, h0b, W1, as1, ad1, h1b, a_s1, a_d1, GB);

  // GAT layer 1
  k_gat1<<<WB, 256, 0, stream>>>(h1b, a_s1, a_d1, off, csrc, b1, h1outb);

  // GAT layer 2
  k_feat2<<<GB, 256, 0, stream>>>(h1outb, W2, as2, ad2, h2b, a_s2, a_d2);
  k_gat2<<<WB, 256, 0, stream>>>(h2b, a_s2, a_d2, off, csrc, b2, h2out);

  // pooling
  k_pool<<<256, 256, 0, stream>>>(h2out, bat, gsum, gmaxk, gcnt);

  // head MLP + log_softmax
  k_final<<<NGR, 64, 0, stream>>>(gsum, gmaxk, gcnt, Wf1, bf1, Wf2, bf2, out);
}

// Round 8
// 230.071 us; speedup vs baseline: 3.0587x; 1.1960x over previous
//
#include <hip/hip_runtime.h>
#include <math.h>

#define NN 50000
#define EE 800000
#define ET 850000    // EE + NN self loops
#define FIN 128
#define HD 64
#define NH 4
#define NGR 64
#define NCL 10
#define NEG 0.2f

typedef unsigned short u16;
typedef unsigned int u32;
typedef __attribute__((ext_vector_type(8))) short short8;
typedef __attribute__((ext_vector_type(4))) float f32x4;

__device__ __forceinline__ float lrelu(float x){ return x > 0.f ? x : NEG * x; }

__device__ __forceinline__ float wsum(float v){
#pragma unroll
  for (int o = 32; o > 0; o >>= 1) v += __shfl_xor(v, o, 64);
  return v;
}
__device__ __forceinline__ float wmax(float v){
#pragma unroll
  for (int o = 32; o > 0; o >>= 1) v = fmaxf(v, __shfl_xor(v, o, 64));
  return v;
}
__device__ __forceinline__ int esrc(const int* ei, int e){ return e < EE ? ei[e] : e - EE; }
__device__ __forceinline__ int edst(const int* ei, int e){ return e < EE ? ei[EE + e] : e - EE; }

__device__ __forceinline__ unsigned f2key(float f){
  unsigned u = __float_as_uint(f);
  return (u & 0x80000000u) ? ~u : (u | 0x80000000u);
}
__device__ __forceinline__ float key2f(unsigned k){
  return (k & 0x80000000u) ? __uint_as_float(k & 0x7fffffffu) : __uint_as_float(~k);
}

// bf16 pack (RNE) / unpack
__device__ __forceinline__ u16 f2b(float f){
  u32 u = __float_as_uint(f);
  u32 r = (u + 0x7FFFu + ((u >> 16) & 1u)) >> 16;
  return (u16)r;
}
__device__ __forceinline__ float b2f(u16 b){ return __uint_as_float(((u32)b) << 16); }
__device__ __forceinline__ u32 pkbf16(float lo, float hi){
  u32 r;
  asm("v_cvt_pk_bf16_f32 %0, %1, %2" : "=v"(r) : "v"(lo), "v"(hi));
  return r;
}
// uniform readlane (idx may be runtime-uniform)
__device__ __forceinline__ int rl(int v, int idx){ return __builtin_amdgcn_readlane(v, idx); }
__device__ __forceinline__ float rlf(float v, int idx){
  return __uint_as_float((u32)__builtin_amdgcn_readlane((int)__float_as_uint(v), idx));
}

// ---------- MFMA GEMM body: C[M,NOUT] = A[M,K] @ B[K,NOUT]; B is f32 (converted here) ----------
template<int K, int NOUT, int CPW, bool RELU_BIAS, bool DOTS1, bool DOTS2, bool AF32>
__device__ __forceinline__ void gemm_body(int bid, u16* As, float* sred,
            const void* __restrict__ Av, const float* __restrict__ Bf,
            const float* __restrict__ bias, const float* __restrict__ att_s, const float* __restrict__ att_d,
            u16* __restrict__ C, float* __restrict__ a_s, float* __restrict__ a_d){
  const u16* A = (const u16*)Av;
  const float* Af = (const float*)Av;
  constexpr int KT = K/32;
  constexpr int NT = CPW/16;
  constexpr int LDK = K + 8;          // +16B pad -> bank stride 4
  int t = threadIdx.x, w = t >> 6, l = t & 63;
  int c0 = w*CPW;
  int l16 = l & 15, kg = l >> 4;

  short8 bf[KT*NT];
#pragma unroll
  for (int kt = 0; kt < KT; ++kt)
#pragma unroll
    for (int nt = 0; nt < NT; ++nt){
      int kbase = kt*32 + kg*8;
      int col = c0 + nt*16 + l16;
      short8 v;
#pragma unroll
      for (int j = 0; j < 8; ++j) v[j] = (short)f2b(Bf[(size_t)(kbase + j)*NOUT + col]);
      bf[kt*NT + nt] = v;
    }
  float bv = 0.f;
  if (RELU_BIAS) bv = bias[c0 + l16];
  float asv[NT], adv[NT];
  if (DOTS1 || DOTS2){
#pragma unroll
    for (int nt = 0; nt < NT; ++nt){
      asv[nt] = att_s[c0 + nt*16 + l16];
      adv[nt] = att_d[c0 + nt*16 + l16];
    }
  }

  for (int ch = 0; ch < 2; ++ch){
    int nb = (bid*2 + ch)*64;
    if (nb >= NN) break;
    __syncthreads();
    constexpr int UPR = K/8;
    for (int u = t; u < 64*UPR; u += 256){
      int r = u / UPR, c = u % UPR;
      int n = nb + r;
      uint4 v = make_uint4(0u,0u,0u,0u);
      if (AF32){
        if (n < NN){
          float4 f0 = *(const float4*)&Af[(size_t)n*K + c*8];
          float4 f1 = *(const float4*)&Af[(size_t)n*K + c*8 + 4];
          v = make_uint4(pkbf16(f0.x,f0.y), pkbf16(f0.z,f0.w), pkbf16(f1.x,f1.y), pkbf16(f1.z,f1.w));
        }
      } else {
        if (n < NN) v = *(const uint4*)&A[(size_t)n*K + c*8];
      }
      *(uint4*)&As[r*LDK + c*8] = v;
    }
    __syncthreads();
#pragma unroll
    for (int rt = 0; rt < 4; ++rt){
      short8 af[KT];
#pragma unroll
      for (int kt = 0; kt < KT; ++kt)
        af[kt] = *(const short8*)&As[(rt*16 + l16)*LDK + kt*32 + kg*8];
      f32x4 acc[NT];
#pragma unroll
      for (int nt = 0; nt < NT; ++nt){
        acc[nt] = (f32x4){0.f,0.f,0.f,0.f};
#pragma unroll
        for (int kt = 0; kt < KT; ++kt)
          acc[nt] = __builtin_amdgcn_mfma_f32_16x16x32_bf16(af[kt], bf[kt*NT + nt], acc[nt], 0, 0, 0);
      }
      int rbase = nb + rt*16 + kg*4;
#pragma unroll
      for (int nt = 0; nt < NT; ++nt)
#pragma unroll
        for (int r4 = 0; r4 < 4; ++r4){
          int n = rbase + r4;
          if (n < NN){
            float v = acc[nt][r4];
            if (RELU_BIAS) v = fmaxf(v + bv, 0.f);
            C[(size_t)n*NOUT + c0 + nt*16 + l16] = f2b(v);
          }
        }
      if (DOTS1){
#pragma unroll
        for (int r4 = 0; r4 < 4; ++r4){
          float ps = 0.f, pd = 0.f;
#pragma unroll
          for (int nt = 0; nt < NT; ++nt){
            ps = fmaf(acc[nt][r4], asv[nt], ps);
            pd = fmaf(acc[nt][r4], adv[nt], pd);
          }
#pragma unroll
          for (int o = 1; o < 16; o <<= 1){
            ps += __shfl_xor(ps, o, 64);
            pd += __shfl_xor(pd, o, 64);
          }
          int n = rbase + r4;
          if (l16 == 0 && n < NN){ a_s[n*NH + w] = ps; a_d[n*NH + w] = pd; }
        }
      }
      if (DOTS2){
#pragma unroll
        for (int r4 = 0; r4 < 4; ++r4){
          float ps = acc[0][r4]*asv[0];
          float pd = acc[0][r4]*adv[0];
#pragma unroll
          for (int o = 1; o < 16; o <<= 1){
            ps += __shfl_xor(ps, o, 64);
            pd += __shfl_xor(pd, o, 64);
          }
          if (l16 == 0){
            int row = rt*16 + kg*4 + r4;
            sred[(w*64 + row)*2]     = ps;
            sred[(w*64 + row)*2 + 1] = pd;
          }
        }
      }
    }
    if (DOTS2){
      __syncthreads();
      if (t < 64){
        int n = nb + t;
        if (n < NN){
          float s = sred[t*2] + sred[(64+t)*2] + sred[(128+t)*2] + sred[(192+t)*2];
          float d = sred[t*2+1] + sred[(64+t)*2+1] + sred[(128+t)*2+1] + sred[(192+t)*2+1];
          a_s[n] = s; a_d[n] = d;
        }
      }
    }
  }
}

// ---------- fused: hist (CSR histogram + rank capture) || proj GEMM ----------
__global__ __launch_bounds__(256) void k_hist_proj(const int* __restrict__ ei, int* __restrict__ cnt,
            int* __restrict__ rank,
            const float* __restrict__ x, const float* __restrict__ Wp, const float* __restrict__ bp,
            u16* __restrict__ h0b, int gb){
  __shared__ u16 As[64*(FIN+8)];
  int b = blockIdx.x;
  if (b < gb){
    gemm_body<128, 64, 16, true, false, false, true>(b, As, nullptr, x, Wp, bp, nullptr, nullptr, h0b, nullptr, nullptr);
  } else {
    int base = (b - gb)*1024;
#pragma unroll
    for (int k = 0; k < 4; ++k){
      int e = base + k*256 + threadIdx.x;
      if (e < ET){
        int d = edst(ei, e);
        rank[e] = atomicAdd(&cnt[d], 1);
      }
    }
  }
}

// ---------- CSR scan kernels ----------
__global__ void k_bsum(const int* __restrict__ cnt, int* __restrict__ bsums){
  int b = blockIdx.x, t = threadIdx.x;
  int i = b*256 + t;
  int v = (i < NN) ? cnt[i] : 0;
  float s = wsum((float)v);
  __shared__ float ws4[4];
  if ((t & 63) == 0) ws4[t >> 6] = s;
  __syncthreads();
  if (t == 0) bsums[b] = (int)(ws4[0] + ws4[1] + ws4[2] + ws4[3] + 0.5f);
}

__global__ void k_boff(const int* __restrict__ bsums, int* __restrict__ boffs, int nb){
  __shared__ int s[256];
  int t = threadIdx.x;
  int v = (t < nb) ? bsums[t] : 0;
  s[t] = v; __syncthreads();
  for (int d = 1; d < 256; d <<= 1){
    int xv = (t >= d) ? s[t-d] : 0;
    __syncthreads();
    s[t] += xv;
    __syncthreads();
  }
  if (t < nb) boffs[t] = s[t] - v;
}

__global__ void k_off(const int* __restrict__ cnt, const int* __restrict__ boffs,
                      int* __restrict__ off){
  int b = blockIdx.x, t = threadIdx.x;
  int i = b*256 + t;
  __shared__ int s[256];
  int v = (i < NN) ? cnt[i] : 0;
  s[t] = v; __syncthreads();
  for (int d = 1; d < 256; d <<= 1){
    int xv = (t >= d) ? s[t-d] : 0;
    __syncthreads();
    s[t] += xv;
    __syncthreads();
  }
  int excl = s[t] - v;
  if (i < NN) off[i] = boffs[b] + excl;
  if (i == NN - 1) off[NN] = boffs[b] + s[t];
}

// ---------- fused: scatter (atomic-free, rank-based) || feat1 GEMM ----------
__global__ __launch_bounds__(256) void k_scat_feat1(const int* __restrict__ ei, const int* __restrict__ off,
            const int* __restrict__ rank, u16* __restrict__ csrc,
            const u16* __restrict__ h0b, const float* __restrict__ W1,
            const float* __restrict__ as1, const float* __restrict__ ad1,
            u16* __restrict__ h1b, float* __restrict__ a_s, float* __restrict__ a_d, int gb){
  __shared__ u16 As[64*(HD+8)];
  int b = blockIdx.x;
  if (b < gb){
    gemm_body<64, 256, 64, false, true, false, false>(b, As, nullptr, h0b, W1, nullptr, as1, ad1, h1b, a_s, a_d);
  } else {
    int base = (b - gb)*1024;
#pragma unroll
    for (int k = 0; k < 4; ++k){
      int e = base + k*256 + threadIdx.x;
      if (e < ET){
        int d = edst(ei, e);
        int s = esrc(ei, e);
        csrc[off[d] + rank[e]] = (u16)s;
      }
    }
  }
}

// ---------- feat2 GEMM with fused layer-2 dots ----------
__global__ __launch_bounds__(256) void k_feat2(const u16* __restrict__ h1outb, const float* __restrict__ W2,
            const float* __restrict__ as2, const float* __restrict__ ad2,
            u16* __restrict__ h2b, float* __restrict__ a_s, float* __restrict__ a_d){
  __shared__ u16 As[64*(256+8)];
  __shared__ float sred[4*64*2];
  gemm_body<256, 64, 16, false, false, true, false>(blockIdx.x, As, sred, h1outb, W2, nullptr, as2, ad2, h2b, a_s, a_d);
}

// ---------- GAT layer-1 aggregation: wave = node, 512B row/load, 8 gathers in flight ----------
__global__ __launch_bounds__(256) void k_gat1(const u16* __restrict__ h1b, const float* __restrict__ a_s,
                       const float* __restrict__ a_d, const int* __restrict__ off,
                       const u16* __restrict__ csrc, const float* __restrict__ b1,
                       u16* __restrict__ h1outb){
  __shared__ float lw[4][4][68];   // [wave][head][64 + 4 pad]
  int wv = threadIdx.x >> 6, l = threadIdx.x & 63;
  int n = blockIdx.x*4 + wv;
  if (n >= NN) return;
  int e0 = off[n], e1 = off[n+1], deg = e1 - e0;
  int j16 = l & 15, h = l >> 4;
  float adst = a_d[n*NH + h];
  float acc0 = 0.f, acc1 = 0.f, acc2 = 0.f, acc3 = 0.f;

#define GAT1_FMA(v, wq) { \
  acc0 = fmaf(b2f(v.x), wq, acc0); acc1 = fmaf(b2f(v.y), wq, acc1); \
  acc2 = fmaf(b2f(v.z), wq, acc2); acc3 = fmaf(b2f(v.w), wq, acc3); }

  if (deg <= 64){
    int sreg[4]; float wreg[4];
#pragma unroll
    for (int c = 0; c < 4; ++c){
      int idx = c*16 + j16;
      int s = (idx < deg) ? (int)csrc[e0 + idx] : 0;
      sreg[c] = s;
      wreg[c] = (idx < deg) ? lrelu(a_s[s*NH + h] + adst) : -3.0e38f;
    }
    float m = fmaxf(fmaxf(wreg[0], wreg[1]), fmaxf(wreg[2], wreg[3]));
#pragma unroll
    for (int o2 = 1; o2 < 16; o2 <<= 1) m = fmaxf(m, __shfl_xor(m, o2, 64));
    float se = 0.f;
#pragma unroll
    for (int c = 0; c < 4; ++c){
      int idx = c*16 + j16;
      float wc = (idx < deg) ? __expf(wreg[c] - m) : 0.f;
      wreg[c] = wc; se += wc;
    }
#pragma unroll
    for (int o2 = 1; o2 < 16; o2 <<= 1) se += __shfl_xor(se, o2, 64);
    float inv = 1.f / (se + 1e-16f);
#pragma unroll
    for (int c = 0; c < 4; ++c) lw[wv][h][c*16 + j16] = wreg[c] * inv;   // same-wave LDS, no barrier

#pragma unroll
    for (int c = 0; c < 4; ++c){
      int cbase = c*16;
      if (cbase < deg){
        int cnt = deg - cbase; if (cnt > 16) cnt = 16;
        int j2 = 0;
        for (; j2 + 8 <= cnt; j2 += 8){
          float4 wqa = *(const float4*)&lw[wv][h][cbase + j2];
          float4 wqb = *(const float4*)&lw[wv][h][cbase + j2 + 4];
          int s0 = rl(sreg[c], j2),   s1 = rl(sreg[c], j2+1);
          int s2 = rl(sreg[c], j2+2), s3 = rl(sreg[c], j2+3);
          int s4 = rl(sreg[c], j2+4), s5 = rl(sreg[c], j2+5);
          int s6 = rl(sreg[c], j2+6), s7 = rl(sreg[c], j2+7);
          ushort4 v0 = *(const ushort4*)(h1b + (size_t)(u32)s0*256 + 4*l);
          ushort4 v1 = *(const ushort4*)(h1b + (size_t)(u32)s1*256 + 4*l);
          ushort4 v2 = *(const ushort4*)(h1b + (size_t)(u32)s2*256 + 4*l);
          ushort4 v3 = *(const ushort4*)(h1b + (size_t)(u32)s3*256 + 4*l);
          ushort4 v4 = *(const ushort4*)(h1b + (size_t)(u32)s4*256 + 4*l);
          ushort4 v5 = *(const ushort4*)(h1b + (size_t)(u32)s5*256 + 4*l);
          ushort4 v6 = *(const ushort4*)(h1b + (size_t)(u32)s6*256 + 4*l);
          ushort4 v7 = *(const ushort4*)(h1b + (size_t)(u32)s7*256 + 4*l);
          GAT1_FMA(v0, wqa.x) GAT1_FMA(v1, wqa.y) GAT1_FMA(v2, wqa.z) GAT1_FMA(v3, wqa.w)
          GAT1_FMA(v4, wqb.x) GAT1_FMA(v5, wqb.y) GAT1_FMA(v6, wqb.z) GAT1_FMA(v7, wqb.w)
        }
        for (; j2 + 4 <= cnt; j2 += 4){
          float4 wq = *(const float4*)&lw[wv][h][cbase + j2];
          int s0 = rl(sreg[c], j2),   s1 = rl(sreg[c], j2+1);
          int s2 = rl(sreg[c], j2+2), s3 = rl(sreg[c], j2+3);
          ushort4 v0 = *(const ushort4*)(h1b + (size_t)(u32)s0*256 + 4*l);
          ushort4 v1 = *(const ushort4*)(h1b + (size_t)(u32)s1*256 + 4*l);
          ushort4 v2 = *(const ushort4*)(h1b + (size_t)(u32)s2*256 + 4*l);
          ushort4 v3 = *(const ushort4*)(h1b + (size_t)(u32)s3*256 + 4*l);
          GAT1_FMA(v0, wq.x) GAT1_FMA(v1, wq.y) GAT1_FMA(v2, wq.z) GAT1_FMA(v3, wq.w)
        }
        for (; j2 < cnt; ++j2){
          float wqs = lw[wv][h][cbase + j2];
          int s = rl(sreg[c], j2);
          ushort4 v = *(const ushort4*)(h1b + (size_t)(u32)s*256 + 4*l);
          GAT1_FMA(v, wqs)
        }
      }
    }
  } else {
    // rare path: any degree
    float m = -3.0e38f;
    for (int i = e0 + j16; i < e1; i += 16){
      int s = csrc[i];
      m = fmaxf(m, lrelu(a_s[s*NH + h] + adst));
    }
#pragma unroll
    for (int o2 = 1; o2 < 16; o2 <<= 1) m = fmaxf(m, __shfl_xor(m, o2, 64));
    float se = 0.f;
    for (int i = e0 + j16; i < e1; i += 16){
      int s = csrc[i];
      se += __expf(lrelu(a_s[s*NH + h] + adst) - m);
    }
#pragma unroll
    for (int o2 = 1; o2 < 16; o2 <<= 1) se += __shfl_xor(se, o2, 64);
    float inv = 1.f / (se + 1e-16f);
    for (int i = e0; i < e1; ++i){
      int s = csrc[i];
      float wq = __expf(lrelu(a_s[s*NH + h] + adst) - m) * inv;
      ushort4 v = *(const ushort4*)(h1b + (size_t)s*256 + 4*l);
      GAT1_FMA(v, wq)
    }
  }
  float4 bv = *(const float4*)&b1[4*l];
  u32 lo = pkbf16(lrelu(acc0 + bv.x), lrelu(acc1 + bv.y));
  u32 hi = pkbf16(lrelu(acc2 + bv.z), lrelu(acc3 + bv.w));
  *(uint2*)&h1outb[(size_t)n*256 + 4*l] = make_uint2(lo, hi);
}

// ---------- GAT layer-2 aggregation: wave = node; 8 edges in flight, 64 lanes x 2B ----------
__global__ __launch_bounds__(256) void k_gat2(const u16* __restrict__ h2b, const float* __restrict__ a_s,
                       const float* __restrict__ a_d, const int* __restrict__ off,
                       const u16* __restrict__ csrc, const float* __restrict__ b2v,
                       float* __restrict__ h2out){
  int wv = threadIdx.x >> 6, l = threadIdx.x & 63;
  int n = blockIdx.x*4 + wv;      // wave == node
  if (n >= NN) return;
  int e0 = off[n], e1 = off[n+1], deg = e1 - e0;
  float adst = a_d[n];
  if (deg <= 64){
    int sA = 0; float alA = -3.0e38f;
    if (l < deg){
      sA = (int)csrc[e0 + l];
      alA = lrelu(a_s[sA] + adst);
    }
    float m = wmax(alA);
    float wA = (l < deg) ? __expf(alA - m) : 0.f;
    float se = wsum(wA);
    wA *= 1.f / (se + 1e-16f);
    float acc = 0.f;
    int idx = 0;
    for (; idx + 8 <= deg; idx += 8){
      int s0 = rl(sA, idx),   s1 = rl(sA, idx+1);
      int s2 = rl(sA, idx+2), s3 = rl(sA, idx+3);
      int s4 = rl(sA, idx+4), s5 = rl(sA, idx+5);
      int s6 = rl(sA, idx+6), s7 = rl(sA, idx+7);
      float w0 = rlf(wA, idx),   w1 = rlf(wA, idx+1);
      float w2 = rlf(wA, idx+2), w3 = rlf(wA, idx+3);
      float w4 = rlf(wA, idx+4), w5 = rlf(wA, idx+5);
      float w6 = rlf(wA, idx+6), w7 = rlf(wA, idx+7);
      float v0 = b2f(h2b[(size_t)(u32)s0*HD + l]);
      float v1 = b2f(h2b[(size_t)(u32)s1*HD + l]);
      float v2 = b2f(h2b[(size_t)(u32)s2*HD + l]);
      float v3 = b2f(h2b[(size_t)(u32)s3*HD + l]);
      float v4 = b2f(h2b[(size_t)(u32)s4*HD + l]);
      float v5 = b2f(h2b[(size_t)(u32)s5*HD + l]);
      float v6 = b2f(h2b[(size_t)(u32)s6*HD + l]);
      float v7 = b2f(h2b[(size_t)(u32)s7*HD + l]);
      acc = fmaf(v0, w0, acc); acc = fmaf(v1, w1, acc);
      acc = fmaf(v2, w2, acc); acc = fmaf(v3, w3, acc);
      acc = fmaf(v4, w4, acc); acc = fmaf(v5, w5, acc);
      acc = fmaf(v6, w6, acc); acc = fmaf(v7, w7, acc);
    }
    for (; idx < deg; ++idx){
      int s = rl(sA, idx);
      float w = rlf(wA, idx);
      acc = fmaf(b2f(h2b[(size_t)(u32)s*HD + l]), w, acc);
    }
    h2out[(size_t)n*HD + l] = lrelu(acc + b2v[l]);
  } else {
    // rare path: any degree; lane = channel
    float m = -3.0e38f;
    for (int i = e0 + l; i < e1; i += 64){
      int s = csrc[i];
      m = fmaxf(m, lrelu(a_s[s] + adst));
    }
    m = wmax(m);
    float se = 0.f;
    for (int i = e0 + l; i < e1; i += 64){
      int s = csrc[i];
      se += __expf(lrelu(a_s[s] + adst) - m);
    }
    se = wsum(se);
    float inv = 1.f / (se + 1e-16f);
    float acc = 0.f;
    for (int i = e0; i < e1; ++i){
      int s = csrc[i];
      acc += b2f(h2b[(size_t)s*HD + l]) * __expf(lrelu(a_s[s] + adst) - m);
    }
    h2out[(size_t)n*HD + l] = lrelu(acc*inv + b2v[l]);
  }
}

// ---------- pooling ----------

__global__ void k_pool(const float* __restrict__ h2out, const int* __restrict__ batch,
                       float* __restrict__ gsum, unsigned* __restrict__ gmaxk, int* __restrict__ gcnt){
  __shared__ float ssum[NGR*HD];
  __shared__ unsigned smax[NGR*HD];
  __shared__ int scnt[NGR];
  int t = threadIdx.x;   // 256
  for (int i = t; i < NGR*HD; i += 256){ ssum[i] = 0.f; smax[i] = 0u; }
  if (t < NGR) scnt[t] = 0;
  __syncthreads();
  int wv = t >> 6, lane = t & 63;
  for (int n = blockIdx.x*4 + wv; n < NN; n += gridDim.x*4){
    int g = batch[n];
    float v = h2out[(size_t)n*HD + lane];
    atomicAdd(&ssum[g*HD + lane], v);
    atomicMax(&smax[g*HD + lane], f2key(v));
    if (lane == 0) atomicAdd(&scnt[g], 1);
  }
  __syncthreads();
  for (int i = t; i < NGR*HD; i += 256){
    atomicAdd(&gsum[i], ssum[i]);
    atomicMax(&gmaxk[i], smax[i]);
  }
  if (t < NGR) atomicAdd(&gcnt[t], scnt[t]);
}

// ---------- final MLP + log_softmax ----------

__global__ void k_final(const float* __restrict__ gsum, const unsigned* __restrict__ gmaxk,
                        const int* __restrict__ gcnt,
                        const float* __restrict__ Wf1, const float* __restrict__ bf1,
                        const float* __restrict__ Wf2, const float* __restrict__ bf2,
                        float* __restrict__ out){
  int g = blockIdx.x, t = threadIdx.x;  // 64 threads
  __shared__ float gv[HD];
  __shared__ float f1[32];
  __shared__ float lg[NCL];
  int c = gcnt[g];
  float dn = fmaxf((float)c, 1.f);
  float mean = gsum[g*HD + t] / dn;
  float mx = (c > 0) ? key2f(gmaxk[g*HD + t]) : 0.f;
  gv[t] = mean + mx;
  __syncthreads();
  if (t < 32){
    float a = bf1[t];
#pragma unroll
    for (int k = 0; k < HD; ++k) a += gv[k] * Wf1[k*32 + t];
    f1[t] = a > 0.f ? a : 0.f;
  }
  __syncthreads();
  if (t < NCL){
    float a = bf2[t];
#pragma unroll
    for (int k = 0; k < 32; ++k) a += f1[k] * Wf2[k*NCL + t];
    lg[t] = a;
  }
  __syncthreads();
  if (t < NCL){
    float m = lg[0];
#pragma unroll
    for (int i = 1; i < NCL; ++i) m = fmaxf(m, lg[i]);
    float s = 0.f;
#pragma unroll
    for (int i = 0; i < NCL; ++i) s += expf(lg[i] - m);
    out[g*NCL + t] = lg[t] - m - logf(s);
  }
}

extern "C" void kernel_launch(void* const* d_in, const int* in_sizes, int n_in,
                              void* d_out, int out_size, void* d_ws, size_t ws_size,
                              hipStream_t stream) {
  const float* x   = (const float*)d_in[0];
  const int*   ei  = (const int*)d_in[1];
  const int*   bat = (const int*)d_in[2];
  const float* Wp  = (const float*)d_in[3];
  const float* bp  = (const float*)d_in[4];
  const float* W1  = (const float*)d_in[5];
  const float* as1 = (const float*)d_in[6];
  const float* ad1 = (const float*)d_in[7];
  const float* b1  = (const float*)d_in[8];
  const float* W2  = (const float*)d_in[9];
  const float* as2 = (const float*)d_in[10];
  const float* ad2 = (const float*)d_in[11];
  const float* b2  = (const float*)d_in[12];
  const float* Wf1 = (const float*)d_in[13];
  const float* bf1 = (const float*)d_in[14];
  const float* Wf2 = (const float*)d_in[15];
  const float* bf2 = (const float*)d_in[16];
  float* out = (float*)d_out;

  char* base = (char*)d_ws;
  size_t o = 0;
  auto alloc = [&](size_t elems) -> char* {   // elems are 4-byte units
    char* p = base + o*4;
    o += (elems + 63) & ~(size_t)63;
    return p;
  };
  u16*   h0b    = (u16*)alloc(1600000);      // [NN,64] bf16
  u16*   h1b    = (u16*)alloc(6400000);      // [NN,256] bf16
  u16*   h1outb = (u16*)alloc(6400000);      // [NN,256] bf16
  u16*   h2b    = (u16*)alloc(800000);       // [NN,64] bf16
  float* h2out  = (float*)alloc(3200000);    // [NN,64] f32
  float* a_s1   = (float*)alloc(200000);
  float* a_d1   = (float*)alloc(200000);
  float* a_s2   = (float*)alloc(50000);
  float* a_d2   = (float*)alloc(50000);
  int*   cnt    = (int*)alloc(50000);
  int*   off    = (int*)alloc(50001);
  int*   rank   = (int*)alloc(850000);
  int*   bsums  = (int*)alloc(256);
  int*   boffs  = (int*)alloc(256);
  u16*   csrc   = (u16*)alloc(425000);       // [ET] u16
  float* gsum   = (float*)alloc(NGR*HD);
  unsigned* gmaxk = (unsigned*)alloc(NGR*HD);
  int*   gcnt   = (int*)alloc(NGR);

  const int NB  = (NN + 255) / 256;     // 196
  const int EB4 = (ET + 1023) / 1024;   // 831 (4 edges/thread)
  const int GB  = (NN + 127) / 128;     // 391 gemm blocks (2x64 rows each)
  const int WB  = (NN + 3) / 4;         // wave-per-node blocks

  hipMemsetAsync(cnt, 0, NN*sizeof(int), stream);
  hipMemsetAsync(gsum, 0, (NGR*HD*2 + 64)*sizeof(int), stream);

  // L1: proj GEMM || CSR histogram (+rank capture)
  k_hist_proj<<<GB + EB4, 256, 0, stream>>>(ei, cnt, rank, x, Wp, bp, h0b, GB);
  // L2-4: CSR scan (small)
  k_bsum<<<NB, 256, 0, stream>>>(cnt, bsums);
  k_boff<<<1, 256, 0, stream>>>(bsums, boffs, NB);
  k_off<<<NB, 256, 0, stream>>>(cnt, boffs, off);
  // L5: feat1 GEMM (+dots) || atomic-free scatter
  k_scat_feat1<<<GB + EB4, 256, 0, stream>>>(ei, off, rank, csrc, h0b, W1, as1, ad1, h1b, a_s1, a_d1, GB);

  // GAT layer 1
  k_gat1<<<WB, 256, 0, stream>>>(h1b, a_s1, a_d1, off, csrc, b1, h1outb);

  // GAT layer 2
  k_feat2<<<GB, 256, 0, stream>>>(h1outb, W2, as2, ad2, h2b, a_s2, a_d2);
  k_gat2<<<WB, 256, 0, stream>>>(h2b, a_s2, a_d2, off, csrc, b2, h2out);

  // pooling
  k_pool<<<256, 256, 0, stream>>>(h2out, bat, gsum, gmaxk, gcnt);

  // head MLP + log_softmax
  k_final<<<NGR, 64, 0, stream>>>(gsum, gmaxk, gcnt, Wf1, bf1, Wf2, bf2, out);
}